// Round 16
// baseline (109.215 us; speedup 1.0000x reference)
//
#include <hip/hip_runtime.h>
#include <hip/hip_bf16.h>
#include <cstdint>
#include <cmath>

#define DM 1024
#define NH 16
#define DK 64
#define NB 2
#define SS 2048
#define MM (NB*SS)   // 4096 rows

typedef unsigned short u16;
typedef uint32_t u32;
typedef __attribute__((ext_vector_type(4))) float f32x4;
typedef __attribute__((ext_vector_type(8))) short s16x8;
typedef __attribute__((ext_vector_type(2))) uint32_t u32x2;

__device__ __forceinline__ u16 f2bf(float f) {
    __hip_bfloat16 h = __float2bfloat16(f);
    return __builtin_bit_cast(u16, h);
}
__device__ __forceinline__ float bf2f(u16 u) {
    u32 x = (u32)u << 16;
    return __builtin_bit_cast(float, x);
}

__device__ __forceinline__ u32 cvtpk(float a, float b) {
    u32 r;
    asm("v_cvt_pk_bf16_f32 %0, %1, %2" : "=v"(r) : "v"(a), "v"(b));
    return r;
}

__device__ __forceinline__ void gload_lds16(void* lds, const void* g) {
    __builtin_amdgcn_global_load_lds(
        (const __attribute__((address_space(1))) uint32_t*)g,
        (__attribute__((address_space(3))) uint32_t*)lds, 16, 0, 0);
}

// XOR-swizzled byte offset within a [rows][128B] LDS tile: 16B slot ^= row&7.
__device__ __forceinline__ int swz(int row, int cb) {
    return row * 128 + ((((cb) >> 4) ^ (row & 7)) << 4) + ((cb) & 15);
}

#define FENCE_BAR  do { __builtin_amdgcn_sched_barrier(0); \
                        __builtin_amdgcn_s_barrier();      \
                        __builtin_amdgcn_sched_barrier(0); } while (0)

// ---------------- prep: cast x -> bf16 AND transpose-cast W (one launch) ----------------
__global__ void mha_prep(const float* __restrict__ x, u16* __restrict__ xb,
                         const float* __restrict__ W0, const float* __restrict__ W1,
                         const float* __restrict__ W2, const float* __restrict__ W3,
                         u16* __restrict__ WtBase) {
    const int bid = blockIdx.x, tid = threadIdx.x;
    if (bid < 4096) {
        int i = (bid * 256 + tid) * 4;
        float4 v = *reinterpret_cast<const float4*>(x + i);
        ushort4 o;
        o.x = f2bf(v.x); o.y = f2bf(v.y); o.z = f2bf(v.z); o.w = f2bf(v.w);
        *reinterpret_cast<ushort4*>(xb + i) = o;
        return;
    }
    __shared__ float t[32][33];
    const int b2 = bid - 4096;
    const int mat = b2 >> 10, rem = b2 & 1023;
    const int cx = rem & 31, cy = rem >> 5;
    const float* W = (mat == 0) ? W0 : (mat == 1) ? W1 : (mat == 2) ? W2 : W3;
    u16* Wt = WtBase + (size_t)mat * DM * DM;
    const int c0 = cx * 32, r0 = cy * 32;
    const int tx = tid & 31, ty = tid >> 5;
#pragma unroll
    for (int i = ty; i < 32; i += 8)
        t[i][tx] = W[(size_t)(r0 + i) * DM + c0 + tx];
    __syncthreads();
#pragma unroll
    for (int i = ty; i < 32; i += 8)
        Wt[(size_t)(c0 + i) * DM + r0 + tx] = f2bf(t[tx][i]);
}

// ---------------- fused QKV GEMM: 256x256 tile, 8-phase schedule ----------------
// Geometry (guide §5 template): BM=BN=256, BK=64, 512 thr = 8 waves (2Mx4N),
// per-wave C = 128x64 = acc[8][4]. LDS 128KB: A[2buf][2half][128][64],
// B likewise at +64KB. Phase = C-quadrant (qa,qb): all 8 waves compute
// quadrant (qa*128, qb*128); wave slice 64x32 -> 16 MFMA/phase.
// T2: staging pre-swizzles the global SOURCE (16B slot ^= row&7) so linear
// gload_lds dest + swz() reads are conflict-free (2-way = free).
// T3/T4: per-phase counted vmcnt {4,4,4} (provable via in-order retire):
//   stages during tile t (phases 0-3) = tile t+1's {A0,B0,A1,B1} -> buf nxt.
//   p0 gate vmcnt(4): completes (t,A0),(t,B0). p1 vmcnt(4): completes (t,A1).
//   p2 vmcnt(4): completes (t,B1). p3: no gate. Last tile drains 4->2->0.
// T5: setprio(1) around each MFMA cluster.
template<int QA, int QB>
__device__ __forceinline__ void phase8(const char* smem, int cur,
                                       int wm, int wn, int lr, int kg,
                                       f32x4 (&acc)[8][4]) {
    const char* Ab = smem + cur * 32768 + QA * 16384;
    const char* Bb = smem + 65536 + cur * 32768 + QB * 16384;
    s16x8 af[4][2], bf[2][2];
#pragma unroll
    for (int m = 0; m < 4; ++m)
#pragma unroll
        for (int ks = 0; ks < 2; ++ks)
            af[m][ks] = *reinterpret_cast<const s16x8*>(Ab + swz(wm * 64 + m * 16 + lr, ks * 64 + kg * 16));
#pragma unroll
    for (int n = 0; n < 2; ++n)
#pragma unroll
        for (int ks = 0; ks < 2; ++ks)
            bf[n][ks] = *reinterpret_cast<const s16x8*>(Bb + swz(wn * 32 + n * 16 + lr, ks * 64 + kg * 16));
    __builtin_amdgcn_s_setprio(1);
#pragma unroll
    for (int m = 0; m < 4; ++m)
#pragma unroll
        for (int n = 0; n < 2; ++n)
#pragma unroll
            for (int ks = 0; ks < 2; ++ks)
                acc[QA * 4 + m][QB * 2 + n] =
                    __builtin_amdgcn_mfma_f32_16x16x32_bf16(af[m][ks], bf[n][ks],
                                                            acc[QA * 4 + m][QB * 2 + n], 0, 0, 0);
    __builtin_amdgcn_s_setprio(0);
}

__global__ __launch_bounds__(512, 2) void mha_gemm_qkv(const u16* __restrict__ xb, const u16* __restrict__ Wt,
                                                       const float* __restrict__ bq, const float* __restrict__ bk,
                                                       const float* __restrict__ bv, u16* __restrict__ qkv) {
    __shared__ __align__(16) char smem[131072];
    const int bid = blockIdx.x;
    const int mtile = bid & 15, ntile = bid >> 4;      // 16 x 12
    const int m0 = mtile * 256, n0g = ntile * 256;
    const int z = n0g >> 10;                            // block-uniform matrix id
    const int n0loc = n0g & 1023;
    const u16* At  = xb + (size_t)m0 * DM;
    const u16* Btm = Wt + (size_t)z * DM * DM + (size_t)n0loc * DM;
    const float* bias = (z == 0) ? bq : (z == 1) ? bk : bv;
    const float scale = (z == 0) ? 0.125f * 1.44269504088896f : 1.0f;
    u16* Cout = qkv + (size_t)z * MM * DM;

    const int tid = threadIdx.x, lane = tid & 63, wid = tid >> 6;
    const int lr = lane & 15, kg = lane >> 4;
    const int wm = wid >> 2, wn = wid & 3;
    f32x4 acc[8][4] = {};

    auto STAGE = [&](int isB, int half, int buf, int kt) {
        char* base = smem + (isB ? 65536 : 0) + buf * 32768 + half * 16384;
        const u16* src = isB ? Btm : At;
#pragma unroll
        for (int i = 0; i < 2; ++i) {
            const int o = tid * 16 + i * 8192;
            const int r = o >> 7, slot = (o >> 4) & 7;
            gload_lds16(base + o,
                        src + (size_t)(half * 128 + r) * DM + kt * 64 + ((slot ^ (r & 7)) << 3));
        }
    };

    // prologue: tile 0's four half-tiles into buf 0 (8 loads/thread)
    STAGE(0, 0, 0, 0); STAGE(1, 0, 0, 0); STAGE(0, 1, 0, 0); STAGE(1, 1, 0, 0);

    for (int t = 0; t < 16; ++t) {
        const int cur = t & 1, nxt = cur ^ 1;
        const bool pf = (t + 1 < 16);
        // ---- p0: needs (t,A0),(t,B0) ----
        asm volatile("s_waitcnt vmcnt(4)" ::: "memory");
        FENCE_BAR;
        if (pf) STAGE(0, 0, nxt, t + 1);
        phase8<0, 0>(smem, cur, wm, wn, lr, kg, acc);
        // ---- p1: needs (t,A1) ----
        if (pf) asm volatile("s_waitcnt vmcnt(4)" ::: "memory");
        else    asm volatile("s_waitcnt vmcnt(2)" ::: "memory");
        FENCE_BAR;
        if (pf) STAGE(1, 0, nxt, t + 1);
        phase8<1, 0>(smem, cur, wm, wn, lr, kg, acc);
        // ---- p2: needs (t,B1) ----
        if (pf) asm volatile("s_waitcnt vmcnt(4)" ::: "memory");
        else    asm volatile("s_waitcnt vmcnt(0)" ::: "memory");
        FENCE_BAR;
        if (pf) STAGE(0, 1, nxt, t + 1);
        phase8<1, 1>(smem, cur, wm, wn, lr, kg, acc);
        // ---- p3: no new half needed ----
        if (pf) STAGE(1, 1, nxt, t + 1);
        phase8<0, 1>(smem, cur, wm, wn, lr, kg, acc);
    }

    // ---- epilogue: direct scatter (r12: staging is perf-neutral) ----
#pragma unroll
    for (int qa = 0; qa < 2; ++qa)
#pragma unroll
        for (int m = 0; m < 4; ++m)
#pragma unroll
            for (int qb = 0; qb < 2; ++qb)
#pragma unroll
                for (int n = 0; n < 2; ++n) {
                    const int colg = n0loc + qb * 128 + wn * 32 + n * 16 + lr; // within z
                    const int h = colg >> 6, d = colg & 63;
                    const float bv2 = bias[colg];
#pragma unroll
                    for (int j = 0; j < 4; ++j) {
                        const int srow = m0 + qa * 128 + wm * 64 + m * 16 + kg * 4 + j;
                        const int bb = srow >> 11, s = srow & (SS - 1);
                        const float v = (acc[qa * 4 + m][qb * 2 + n][j] + bv2) * scale;
                        if (z == 0) {
                            Cout[(((size_t)(bb * NH + h) * SS + s) * DK) + d] = f2bf(v);
                        } else {
                            const int kt = s >> 6, r = s & 63;
                            const size_t tb = ((size_t)(bb * NH + h) * 32 + kt) * 4096;
                            const int bo = (z == 1) ? swz(r, d * 2)
                                                    : swz(d, (r >> 1) * 4 + (r & 1) * 2);
                            Cout[tb + (bo >> 1)] = f2bf(v);
                        }
                    }
                }
}

// ---------------- gemm_out: r15 128x128 dbuf structure (unchanged) ----------------
__device__ __forceinline__ void gemm_loop_db(const u16* __restrict__ A, const u16* __restrict__ Bt,
                                             int m0, int n0, char* smem /*64KB*/, f32x4 acc[4][4]) {
    const int tid = threadIdx.x;
    const int wave = tid >> 6, lane = tid & 63;
    const int lr = lane & 15, kg = lane >> 4;
    const int wr = wave >> 1, wc = wave & 1;

    auto STAGE = [&](int buf, int k0) {
        char* As = smem + buf * 32768;
        char* Bs = As + 16384;
#pragma unroll
        for (int i = 0; i < 4; ++i) {
            const int o   = ((wave * 4 + i) * 64 + lane) * 16;
            const int row = o >> 7;
            const int kb  = o & 127;
            gload_lds16(As + o, A  + (size_t)(m0 + row) * DM + k0 + (kb >> 1));
            gload_lds16(Bs + o, Bt + (size_t)(n0 + row) * DM + k0 + (kb >> 1));
        }
    };

    STAGE(0, 0);
    for (int t = 0; t < 16; ++t) {
        if (t + 1 < 16) {
            STAGE((t + 1) & 1, (t + 1) * 64);
            asm volatile("s_waitcnt vmcnt(8)" ::: "memory");
        } else {
            asm volatile("s_waitcnt vmcnt(0)" ::: "memory");
        }
        FENCE_BAR;
        const u16 (*As)[64] = reinterpret_cast<const u16(*)[64]>(smem + (t & 1) * 32768);
        const u16 (*Bs)[64] = reinterpret_cast<const u16(*)[64]>(smem + (t & 1) * 32768 + 16384);
#pragma unroll
        for (int kk = 0; kk < 64; kk += 32) {
            s16x8 a[4], b[4];
#pragma unroll
            for (int m = 0; m < 4; ++m)
                a[m] = *reinterpret_cast<const s16x8*>(&As[wr * 64 + m * 16 + lr][kk + kg * 8]);
#pragma unroll
            for (int n = 0; n < 4; ++n)
                b[n] = *reinterpret_cast<const s16x8*>(&Bs[wc * 64 + n * 16 + lr][kk + kg * 8]);
#pragma unroll
            for (int m = 0; m < 4; ++m)
#pragma unroll
                for (int n = 0; n < 4; ++n)
                    acc[m][n] = __builtin_amdgcn_mfma_f32_16x16x32_bf16(a[m], b[n], acc[m][n], 0, 0, 0);
        }
        FENCE_BAR;
    }
}

__global__ __launch_bounds__(256, 2) void mha_gemm_out(const u16* __restrict__ AO, const u16* __restrict__ WoT,
                                                       const float* __restrict__ bo, float* __restrict__ out) {
    __shared__ __align__(16) char smem[65536];
    const int m0 = blockIdx.x * 128, n0 = blockIdx.y * 128;

    f32x4 acc[4][4] = {};
    gemm_loop_db(AO, WoT, m0, n0, smem, acc);

    const int tid = threadIdx.x;
    const int wave = tid >> 6, lane = tid & 63;
    const int lr = lane & 15, kg = lane >> 4;
    const int wr = wave >> 1, wc = wave & 1;
#pragma unroll
    for (int m = 0; m < 4; ++m)
#pragma unroll
        for (int n = 0; n < 4; ++n) {
            const int col = n0 + wc * 64 + n * 16 + lr;
            const float bv = bo[col];
#pragma unroll
            for (int j2 = 0; j2 < 4; ++j2) {
                const int row = m0 + wr * 64 + m * 16 + kg * 4 + j2;
                out[(size_t)row * DM + col] = acc[m][n][j2] + bv;
            }
        }
}

// ---------------- flash attention v10 (unchanged): DMA staging ----------------
__device__ const unsigned char JQT[48] = {
    15,31,30,31, 14,29,30,28,29, 13,27,28,26,27, 12,25,26,24,25,
    11,23,24,22,23, 10,21,22,20,21, 9,19,20,18,19, 8,17,18,16,17,
    7,16, 6,5,4,3,2,1,0};
__device__ const unsigned char JKS[48] = {
    0,0,15,16, 0,0,0,14,15, 0,0,0,13,14, 0,0,0,12,13,
    0,0,0,11,12, 0,0,0,10,11, 0,0,0,9,10, 0,0,0,8,9,
    0,0, 0,0,0,0,0,0,0};
__device__ const unsigned char JKL[48] = {
    16,16,16,16, 15,15,15,15,15, 14,14,14,14,14, 13,13,13,13,13,
    12,12,12,12,12, 11,11,11,11,11, 10,10,10,10,10, 9,9,9,9,9,
    8,8, 7,6,5,4,3,2,1};
__device__ const unsigned char JSL[48] = {
    255,30,29,31, 255,26,28,25,27, 255,22,24,21,23, 255,18,20,17,19,
    255,14,16,13,15, 255,10,12,9,11, 255,6,8,5,7, 255,2,4,1,3,
    255,0, 255,255,255,255,255,255,255};

__global__ __launch_bounds__(256, 4) void mha_attn(const u16* __restrict__ Qb, const u16* __restrict__ Kswz,
                                                   const u16* __restrict__ Vtswz, u16* __restrict__ AO,
                                                   u16* __restrict__ Opart, float* __restrict__ lpart) {
    __shared__ __align__(16) char lds[40960];

    const int bid = blockIdx.x;
    const int bh  = bid & 31;
    const int job = bid >> 5;
    const int qt   = JQT[job];
    const int kst  = JKS[job];
    const int klen = JKL[job];
    const int slot = JSL[job];
    const int qb = qt * 64;

    const int tid = threadIdx.x, w = tid >> 6, lane = tid & 63;
    const int lr = lane & 15, kg = lane >> 4;

    const u16* Qh = Qb + (size_t)bh * SS * DK;
    const char* Ktiles = (const char*)(Kswz  + (size_t)bh * 32 * 4096);
    const char* Vtiles = (const char*)(Vtswz + (size_t)bh * 32 * 4096);
    const int bb = bh >> 4, hh = bh & (NH - 1);
    char* psb = lds + 32768 + w * 2048;
    const int o = tid * 16;

    const int qrow = qb + w * 16 + lr;
    const s16x8 qf0 = *reinterpret_cast<const s16x8*>(Qh + (size_t)qrow * DK + kg * 8);
    const s16x8 qf1 = *reinterpret_cast<const s16x8*>(Qh + (size_t)qrow * DK + 32 + kg * 8);
    f32x4 accO[4] = {};
    float lp = 0.f;

    const int kend = kst + klen;
    {
        const char* Kt = Ktiles + kst * 8192;
        const char* Vt = Vtiles + kst * 8192;
        gload_lds16(lds + o,                 Kt + o);
        gload_lds16(lds + o + 4096,          Kt + o + 4096);
        gload_lds16(lds + 16384 + o,         Vt + o);
        gload_lds16(lds + 16384 + o + 4096,  Vt + o + 4096);
    }

    for (int t = kst; t < kend; ++t) {
        const int buf = (t - kst) & 1;
        asm volatile("s_waitcnt vmcnt(0)" ::: "memory");
        __syncthreads();
        if (t + 1 < kend) {
            const char* Kt = Ktiles + (t + 1) * 8192;
            const char* Vt = Vtiles + (t + 1) * 8192;
            char* kb2 = lds + (buf ^ 1) * 8192;
            char* vb2 = lds + 16384 + (buf ^ 1) * 8192;
            gload_lds16(kb2 + o,        Kt + o);
            gload_lds16(kb2 + o + 4096, Kt + o + 4096);
            gload_lds16(vb2 + o,        Vt + o);
            gload_lds16(vb2 + o + 4096, Vt + o + 4096);
        }
        const char* ksb = lds + buf * 8192;
        const char* vtb = lds + 16384 + buf * 8192;

        f32x4 sc[4];
#pragma unroll
        for (int f = 0; f < 4; ++f) {
            s16x8 kf0 = *reinterpret_cast<const s16x8*>(ksb + swz(f * 16 + lr, kg * 16));
            s16x8 kf1 = *reinterpret_cast<const s16x8*>(ksb + swz(f * 16 + lr, 64 + kg * 16));
            f32x4 s = {};
            s = __builtin_amdgcn_mfma_f32_16x16x32_bf16(kf0, qf0, s, 0, 0, 0);
            s = __builtin_amdgcn_mfma_f32_16x16x32_bf16(kf1, qf1, s, 0, 0, 0);
            sc[f] = s;
        }
#pragma unroll
        for (int f = 0; f < 4; ++f)
#pragma unroll
            for (int j = 0; j < 4; ++j)
                sc[f][j] = __builtin_amdgcn_exp2f(sc[f][j]);
        if (t == qt) {
            const int qloc = w * 16 + lr;
#pragma unroll
            for (int f = 0; f < 4; ++f) {
                const int kc = f * 16 + kg * 4;
#pragma unroll
                for (int j = 0; j < 4; ++j)
                    if (kc + j > qloc) sc[f][j] = 0.f;
            }
        }
        float fs0 = 0.f, fs1 = 0.f;
#pragma unroll
        for (int f = 0; f < 4; ++f) {
            u32x2 pp;
            pp[0] = cvtpk(sc[f][0], sc[f][1]);
            pp[1] = cvtpk(sc[f][2], sc[f][3]);
            *reinterpret_cast<u32x2*>(psb + swz(lr, f * 32 + kg * 8)) = pp;
            const float s01 = sc[f][0] + sc[f][1], s23 = sc[f][2] + sc[f][3];
            if (f & 1) fs1 += s01 + s23; else fs0 += s01 + s23;
        }
        lp += fs0 + fs1;

        const s16x8 pf0 = *reinterpret_cast<const s16x8*>(psb + swz(lr, kg * 16));
        const s16x8 pf1 = *reinterpret_cast<const s16x8*>(psb + swz(lr, 64 + kg * 16));
#pragma unroll
        for (int db = 0; db < 4; ++db) {
            s16x8 vf0 = *reinterpret_cast<const s16x8*>(vtb + swz(db * 16 + lr, kg * 16));
            s16x8 vf1 = *reinterpret_cast<const s16x8*>(vtb + swz(db * 16 + lr, 64 + kg * 16));
            accO[db] = __builtin_amdgcn_mfma_f32_16x16x32_bf16(pf0, vf0, accO[db], 0, 0, 0);
            accO[db] = __builtin_amdgcn_mfma_f32_16x16x32_bf16(pf1, vf1, accO[db], 0, 0, 0);
        }
    }

    lp += __shfl_xor(lp, 16, 64);
    lp += __shfl_xor(lp, 32, 64);

    if (slot == 255) {
        float inv[4];
#pragma unroll
        for (int j = 0; j < 4; ++j)
            inv[j] = 1.0f / __shfl(lp, kg * 4 + j, 64);
#pragma unroll
        for (int db = 0; db < 4; ++db) {
            const int d = db * 16 + lr;
#pragma unroll
            for (int j = 0; j < 4; ++j) {
                const int s = qb + w * 16 + kg * 4 + j;
                AO[((size_t)(bb * SS + s)) * DM + hh * DK + d] = f2bf(accO[db][j] * inv[j]);
            }
        }
    } else {
        const int idx = bh * 32 + slot;
        u16* Od = Opart + (size_t)idx * 4096;
#pragma unroll
        for (int db = 0; db < 4; ++db) {
            const int d = db * 16 + lr;
#pragma unroll
            for (int j = 0; j < 4; ++j)
                Od[(w * 16 + kg * 4 + j) * 64 + d] = f2bf(accO[db][j]);
        }
        if (lane < 16)
            lpart[idx * 64 + w * 16 + lane] = lp;
    }
}

// combine partials for split q-tiles: AO = (O0+O1)/(l0+l1)
__global__ __launch_bounds__(256) void mha_combine(const u16* __restrict__ Opart,
                                                   const float* __restrict__ lpart,
                                                   u16* __restrict__ AO) {
    const int blk = blockIdx.x;          // 0..511
    const int bh = blk & 31, q = blk >> 5;
    const int qt = 16 + q;
    const int t = threadIdx.x;
    const int row = t >> 2, c0 = (t & 3) * 16;
    const int idx0 = bh * 32 + q * 2;
    const u16* O0 = Opart + (size_t)idx0 * 4096 + row * 64 + c0;
    const u16* O1 = O0 + 4096;
    const float l = lpart[idx0 * 64 + row] + lpart[(idx0 + 1) * 64 + row];
    const float inv = 1.0f / l;
    const int bb = bh >> 4, hh = bh & (NH - 1);
    const int s = qt * 64 + row;
    u16* dst = AO + ((size_t)(bb * SS + s)) * DM + hh * DK + c0;
#pragma unroll
    for (int h = 0; h < 2; ++h) {
        s16x8 a = *reinterpret_cast<const s16x8*>(O0 + h * 8);
        s16x8 b = *reinterpret_cast<const s16x8*>(O1 + h * 8);
        u16* ap = (u16*)&a; u16* bp = (u16*)&b;
        u16 ov[8];
#pragma unroll
        for (int i = 0; i < 8; ++i)
            ov[i] = f2bf((bf2f(ap[i]) + bf2f(bp[i])) * inv);
        *reinterpret_cast<ushort4*>(dst + h * 8) = *reinterpret_cast<ushort4*>(&ov[0]);
        *reinterpret_cast<ushort4*>(dst + h * 8 + 4) = *reinterpret_cast<ushort4*>(&ov[4]);
    }
}

extern "C" void kernel_launch(void* const* d_in, const int* in_sizes, int n_in,
                              void* d_out, int out_size, void* d_ws, size_t ws_size,
                              hipStream_t stream) {
    const float* x  = (const float*)d_in[0];
    const float* Wq = (const float*)d_in[2];
    const float* bq = (const float*)d_in[3];
    const float* Wk = (const float*)d_in[4];
    const float* bk = (const float*)d_in[5];
    const float* Wv = (const float*)d_in[6];
    const float* bv = (const float*)d_in[7];
    const float* Wo = (const float*)d_in[8];
    const float* bo = (const float*)d_in[9];
    float* out = (float*)d_out;

    char* ws = (char*)d_ws;
    u16* xb  = (u16*)(ws);                       // 8 MB (dead after gemm_qkv)
    u16* Wt  = (u16*)(ws + ((size_t)8  << 20));  // 8 MB (Wq,Wk,Wv dead after qkv; Wo^T kept)
    u16* qkv = (u16*)(ws + ((size_t)16 << 20));  // 24 MB: Q | K-swz tiles | V^T-swz tiles
    u16* AO  = (u16*)(ws + ((size_t)40 << 20));  // 8 MB
    u16*   Opart = (u16*)(ws);                       // 8 MB over xb
    float* lpart = (float*)(ws + ((size_t)8 << 20)); // 256 KB over Wq^T

    mha_prep<<<dim3(8192), dim3(256), 0, stream>>>(x, xb, Wq, Wk, Wv, Wo, Wt);
    mha_gemm_qkv<<<dim3(192), dim3(512), 0, stream>>>(xb, Wt, bq, bk, bv, qkv);
    mha_attn<<<dim3(1536), dim3(256), 0, stream>>>(qkv, qkv + (size_t)4194304, qkv + (size_t)8388608,
                                                   AO, Opart, lpart);
    mha_combine<<<dim3(512), dim3(256), 0, stream>>>(Opart, lpart, AO);
    mha_gemm_out<<<dim3(32, 8), dim3(256), 0, stream>>>(AO, Wt + (size_t)3 * DM * DM, bo, out);
}

// Round 17
// 103.534 us; speedup vs baseline: 1.0549x; 1.0549x over previous
//
#include <hip/hip_runtime.h>
#include <hip/hip_bf16.h>
#include <cstdint>
#include <cmath>

#define DM 1024
#define NH 16
#define DK 64
#define NB 2
#define SS 2048
#define MM (NB*SS)   // 4096 rows

typedef unsigned short u16;
typedef uint32_t u32;
typedef __attribute__((ext_vector_type(4))) float f32x4;
typedef __attribute__((ext_vector_type(8))) short s16x8;
typedef __attribute__((ext_vector_type(2))) uint32_t u32x2;

__device__ __forceinline__ u16 f2bf(float f) {
    __hip_bfloat16 h = __float2bfloat16(f);
    return __builtin_bit_cast(u16, h);
}
__device__ __forceinline__ float bf2f(u16 u) {
    u32 x = (u32)u << 16;
    return __builtin_bit_cast(float, x);
}

__device__ __forceinline__ u32 cvtpk(float a, float b) {
    u32 r;
    asm("v_cvt_pk_bf16_f32 %0, %1, %2" : "=v"(r) : "v"(a), "v"(b));
    return r;
}

__device__ __forceinline__ void gload_lds16(void* lds, const void* g) {
    __builtin_amdgcn_global_load_lds(
        (const __attribute__((address_space(1))) uint32_t*)g,
        (__attribute__((address_space(3))) uint32_t*)lds, 16, 0, 0);
}

// XOR-swizzled byte offset within a [rows][128B] LDS tile: 16B slot ^= row&7.
__device__ __forceinline__ int swz(int row, int cb) {
    return row * 128 + ((((cb) >> 4) ^ (row & 7)) << 4) + ((cb) & 15);
}

#define FENCE_BAR  do { __builtin_amdgcn_sched_barrier(0); \
                        __builtin_amdgcn_s_barrier();      \
                        __builtin_amdgcn_sched_barrier(0); } while (0)

// ---------------- prep: cast x -> bf16 AND transpose-cast W (one launch) ----------------
__global__ void mha_prep(const float* __restrict__ x, u16* __restrict__ xb,
                         const float* __restrict__ W0, const float* __restrict__ W1,
                         const float* __restrict__ W2, const float* __restrict__ W3,
                         u16* __restrict__ WtBase) {
    const int bid = blockIdx.x, tid = threadIdx.x;
    if (bid < 4096) {
        int i = (bid * 256 + tid) * 4;
        float4 v = *reinterpret_cast<const float4*>(x + i);
        ushort4 o;
        o.x = f2bf(v.x); o.y = f2bf(v.y); o.z = f2bf(v.z); o.w = f2bf(v.w);
        *reinterpret_cast<ushort4*>(xb + i) = o;
        return;
    }
    __shared__ float t[32][33];
    const int b2 = bid - 4096;
    const int mat = b2 >> 10, rem = b2 & 1023;
    const int cx = rem & 31, cy = rem >> 5;
    const float* W = (mat == 0) ? W0 : (mat == 1) ? W1 : (mat == 2) ? W2 : W3;
    u16* Wt = WtBase + (size_t)mat * DM * DM;
    const int c0 = cx * 32, r0 = cy * 32;
    const int tx = tid & 31, ty = tid >> 5;
#pragma unroll
    for (int i = ty; i < 32; i += 8)
        t[i][tx] = W[(size_t)(r0 + i) * DM + c0 + tx];
    __syncthreads();
#pragma unroll
    for (int i = ty; i < 32; i += 8)
        Wt[(size_t)(c0 + i) * DM + r0 + tx] = f2bf(t[tx][i]);
}

// ---------------- 128x128 tile bf16 MFMA GEMM main loop (r13-verified) ----------------
__device__ __forceinline__ void gemm_loop(const u16* __restrict__ A, const u16* __restrict__ Bt,
                                          int m0, int n0,
                                          u16 (*As)[64], u16 (*Bs)[64], f32x4 acc[4][4]) {
    const int tid = threadIdx.x;
    const int wave = tid >> 6, lane = tid & 63;
    const int lr = lane & 15, kg = lane >> 4;
    const int wr = wave >> 1, wc = wave & 1;

    for (int k0 = 0; k0 < DM; k0 += 64) {
        __syncthreads();
#pragma unroll
        for (int i = 0; i < 4; ++i) {
            const int o   = ((wave * 4 + i) * 64 + lane) * 16;
            const int row = o >> 7;
            const int kb  = o & 127;
            gload_lds16((char*)As + o, A  + (size_t)(m0 + row) * DM + k0 + (kb >> 1));
            gload_lds16((char*)Bs + o, Bt + (size_t)(n0 + row) * DM + k0 + (kb >> 1));
        }
        __syncthreads();
#pragma unroll
        for (int kk = 0; kk < 64; kk += 32) {
            s16x8 a[4], b[4];
#pragma unroll
            for (int m = 0; m < 4; ++m)
                a[m] = *reinterpret_cast<const s16x8*>(&As[wr * 64 + m * 16 + lr][kk + kg * 8]);
#pragma unroll
            for (int n = 0; n < 4; ++n)
                b[n] = *reinterpret_cast<const s16x8*>(&Bs[wc * 64 + n * 16 + lr][kk + kg * 8]);
#pragma unroll
            for (int m = 0; m < 4; ++m)
#pragma unroll
                for (int n = 0; n < 4; ++n)
                    acc[m][n] = __builtin_amdgcn_mfma_f32_16x16x32_bf16(a[m], b[n], acc[m][n], 0, 0, 0);
        }
    }
}

// QKV GEMM: r13-verified best config (42.7us): 128x128, 2-barrier, 32KB LDS,
// 3 blocks/CU, XCD-band mapping, LDS-image epilogue + coalesced copy-out.
__global__ __launch_bounds__(256, 2) void mha_gemm_qkv(const u16* __restrict__ xb, const u16* __restrict__ Wt,
                                                       const float* __restrict__ bq, const float* __restrict__ bk,
                                                       const float* __restrict__ bv, u16* __restrict__ qkv) {
    __shared__ __align__(16) char smem[32768];
    u16 (*As)[64] = reinterpret_cast<u16(*)[64]>(smem);
    u16 (*Bs)[64] = reinterpret_cast<u16(*)[64]>(smem + 16384);

    const int bid = blockIdx.x;
    const int j = bid & 7, r = bid >> 3;         // 768 = 8 XCDs x 96
    const int bx = j * 4 + (r & 3);
    const int by = (r >> 2) & 7;
    const int z  = r >> 5;                        // 0..2
    const int m0 = bx * 128, n0 = by * 128;

    const float* bias = (z == 0) ? bq : (z == 1) ? bk : bv;
    const float scale = (z == 0) ? 0.125f * 1.44269504088896f : 1.0f;
    u16* Cout = qkv + (size_t)z * MM * DM;

    f32x4 acc[4][4] = {};
    gemm_loop(xb, Wt + (size_t)z * DM * DM, m0, n0, As, Bs, acc);

    const int tid = threadIdx.x;
    const int wave = tid >> 6, lane = tid & 63;
    const int lr = lane & 15, kg = lane >> 4;
    const int wr = wave >> 1, wc = wave & 1;

    __syncthreads();   // all waves done reading As/Bs before image writes
    // ---- acc -> LDS image (32KB, bijective) ----
#pragma unroll
    for (int m = 0; m < 4; ++m)
#pragma unroll
        for (int n = 0; n < 4; ++n) {
            const int col = wc * 64 + n * 16 + lr;        // 0..127 within block
            const float bv2 = bias[n0 + col];
#pragma unroll
            for (int j2 = 0; j2 < 4; ++j2) {
                const int row = wr * 64 + m * 16 + kg * 4 + j2;  // 0..127
                const float v = (acc[m][n][j2] + bv2) * scale;
                int imgoff;
                if (z == 0) {
                    imgoff = row * 256 + (col >> 6) * 128 + (col & 63) * 2;
                } else if (z == 1) {
                    imgoff = ((row >> 6) * 2 + (col >> 6)) * 8192 + swz(row & 63, (col & 63) * 2);
                } else {
                    imgoff = ((row >> 6) * 2 + (col >> 6)) * 8192
                           + swz(col & 63, ((row & 63) >> 1) * 4 + (row & 1) * 2);
                }
                *reinterpret_cast<u16*>(smem + imgoff) = f2bf(v);
            }
        }
    __syncthreads();
    // ---- LDS -> global, coalesced 16B chunks ----
    const int bb = m0 >> 11, s0 = m0 & (SS - 1);
    const int kt0 = s0 >> 6, h0 = n0 >> 6;
#pragma unroll
    for (int it = 0; it < 8; ++it) {
        const int c = it * 256 + tid;     // 16B chunk id, 0..2047
        const s16x8 v = *reinterpret_cast<const s16x8*>(smem + c * 16);
        u16* dst;
        if (z == 0) {
            const int srow = c >> 4, inrow = c & 15;
            const int hl = inrow >> 3, d0 = (inrow & 7) * 8;
            dst = Cout + (((size_t)(bb * NH + h0 + hl) * SS + (s0 + srow)) * DK) + d0;
        } else {
            const int quad = c >> 9, off = (c & 511) * 8;   // u16 units
            const int ktl = quad >> 1, hl = quad & 1;
            dst = Cout + ((size_t)(bb * NH + h0 + hl) * 32 + kt0 + ktl) * 4096 + off;
        }
        *reinterpret_cast<s16x8*>(dst) = v;
    }
}

// ---------------- gemm_out: counted-vmcnt dbuf (r15-verified) ----------------
__device__ __forceinline__ void gemm_loop_db(const u16* __restrict__ A, const u16* __restrict__ Bt,
                                             int m0, int n0, char* smem /*64KB*/, f32x4 acc[4][4]) {
    const int tid = threadIdx.x;
    const int wave = tid >> 6, lane = tid & 63;
    const int lr = lane & 15, kg = lane >> 4;
    const int wr = wave >> 1, wc = wave & 1;

    auto STAGE = [&](int buf, int k0) {
        char* As = smem + buf * 32768;
        char* Bs = As + 16384;
#pragma unroll
        for (int i = 0; i < 4; ++i) {
            const int o   = ((wave * 4 + i) * 64 + lane) * 16;
            const int row = o >> 7;
            const int kb  = o & 127;
            gload_lds16(As + o, A  + (size_t)(m0 + row) * DM + k0 + (kb >> 1));
            gload_lds16(Bs + o, Bt + (size_t)(n0 + row) * DM + k0 + (kb >> 1));
        }
    };

    STAGE(0, 0);
    for (int t = 0; t < 16; ++t) {
        if (t + 1 < 16) {
            STAGE((t + 1) & 1, (t + 1) * 64);
            asm volatile("s_waitcnt vmcnt(8)" ::: "memory");
        } else {
            asm volatile("s_waitcnt vmcnt(0)" ::: "memory");
        }
        FENCE_BAR;
        const u16 (*As)[64] = reinterpret_cast<const u16(*)[64]>(smem + (t & 1) * 32768);
        const u16 (*Bs)[64] = reinterpret_cast<const u16(*)[64]>(smem + (t & 1) * 32768 + 16384);
#pragma unroll
        for (int kk = 0; kk < 64; kk += 32) {
            s16x8 a[4], b[4];
#pragma unroll
            for (int m = 0; m < 4; ++m)
                a[m] = *reinterpret_cast<const s16x8*>(&As[wr * 64 + m * 16 + lr][kk + kg * 8]);
#pragma unroll
            for (int n = 0; n < 4; ++n)
                b[n] = *reinterpret_cast<const s16x8*>(&Bs[wc * 64 + n * 16 + lr][kk + kg * 8]);
#pragma unroll
            for (int m = 0; m < 4; ++m)
#pragma unroll
                for (int n = 0; n < 4; ++n)
                    acc[m][n] = __builtin_amdgcn_mfma_f32_16x16x32_bf16(a[m], b[n], acc[m][n], 0, 0, 0);
        }
        FENCE_BAR;
    }
}

__global__ __launch_bounds__(256, 2) void mha_gemm_out(const u16* __restrict__ AO, const u16* __restrict__ WoT,
                                                       const float* __restrict__ bo, float* __restrict__ out) {
    __shared__ __align__(16) char smem[65536];
    const int m0 = blockIdx.x * 128, n0 = blockIdx.y * 128;

    f32x4 acc[4][4] = {};
    gemm_loop_db(AO, WoT, m0, n0, smem, acc);

    const int tid = threadIdx.x;
    const int wave = tid >> 6, lane = tid & 63;
    const int lr = lane & 15, kg = lane >> 4;
    const int wr = wave >> 1, wc = wave & 1;
#pragma unroll
    for (int m = 0; m < 4; ++m)
#pragma unroll
        for (int n = 0; n < 4; ++n) {
            const int col = n0 + wc * 64 + n * 16 + lr;
            const float bv = bo[col];
#pragma unroll
            for (int j2 = 0; j2 < 4; ++j2) {
                const int row = m0 + wr * 64 + m * 16 + kg * 4 + j2;
                out[(size_t)row * DM + col] = acc[m][n][j2] + bv;
            }
        }
}

// ---------------- flash attention v10 (unchanged): DMA staging ----------------
__device__ const unsigned char JQT[48] = {
    15,31,30,31, 14,29,30,28,29, 13,27,28,26,27, 12,25,26,24,25,
    11,23,24,22,23, 10,21,22,20,21, 9,19,20,18,19, 8,17,18,16,17,
    7,16, 6,5,4,3,2,1,0};
__device__ const unsigned char JKS[48] = {
    0,0,15,16, 0,0,0,14,15, 0,0,0,13,14, 0,0,0,12,13,
    0,0,0,11,12, 0,0,0,10,11, 0,0,0,9,10, 0,0,0,8,9,
    0,0, 0,0,0,0,0,0,0};
__device__ const unsigned char JKL[48] = {
    16,16,16,16, 15,15,15,15,15, 14,14,14,14,14, 13,13,13,13,13,
    12,12,12,12,12, 11,11,11,11,11, 10,10,10,10,10, 9,9,9,9,9,
    8,8, 7,6,5,4,3,2,1};
__device__ const unsigned char JSL[48] = {
    255,30,29,31, 255,26,28,25,27, 255,22,24,21,23, 255,18,20,17,19,
    255,14,16,13,15, 255,10,12,9,11, 255,6,8,5,7, 255,2,4,1,3,
    255,0, 255,255,255,255,255,255,255};

__global__ __launch_bounds__(256, 4) void mha_attn(const u16* __restrict__ Qb, const u16* __restrict__ Kswz,
                                                   const u16* __restrict__ Vtswz, u16* __restrict__ AO,
                                                   u16* __restrict__ Opart, float* __restrict__ lpart) {
    __shared__ __align__(16) char lds[40960];

    const int bid = blockIdx.x;
    const int bh  = bid & 31;
    const int job = bid >> 5;
    const int qt   = JQT[job];
    const int kst  = JKS[job];
    const int klen = JKL[job];
    const int slot = JSL[job];
    const int qb = qt * 64;

    const int tid = threadIdx.x, w = tid >> 6, lane = tid & 63;
    const int lr = lane & 15, kg = lane >> 4;

    const u16* Qh = Qb + (size_t)bh * SS * DK;
    const char* Ktiles = (const char*)(Kswz  + (size_t)bh * 32 * 4096);
    const char* Vtiles = (const char*)(Vtswz + (size_t)bh * 32 * 4096);
    const int bb = bh >> 4, hh = bh & (NH - 1);
    char* psb = lds + 32768 + w * 2048;
    const int o = tid * 16;

    const int qrow = qb + w * 16 + lr;
    const s16x8 qf0 = *reinterpret_cast<const s16x8*>(Qh + (size_t)qrow * DK + kg * 8);
    const s16x8 qf1 = *reinterpret_cast<const s16x8*>(Qh + (size_t)qrow * DK + 32 + kg * 8);
    f32x4 accO[4] = {};
    float lp = 0.f;

    const int kend = kst + klen;
    {
        const char* Kt = Ktiles + kst * 8192;
        const char* Vt = Vtiles + kst * 8192;
        gload_lds16(lds + o,                 Kt + o);
        gload_lds16(lds + o + 4096,          Kt + o + 4096);
        gload_lds16(lds + 16384 + o,         Vt + o);
        gload_lds16(lds + 16384 + o + 4096,  Vt + o + 4096);
    }

    for (int t = kst; t < kend; ++t) {
        const int buf = (t - kst) & 1;
        asm volatile("s_waitcnt vmcnt(0)" ::: "memory");
        __syncthreads();
        if (t + 1 < kend) {
            const char* Kt = Ktiles + (t + 1) * 8192;
            const char* Vt = Vtiles + (t + 1) * 8192;
            char* kb2 = lds + (buf ^ 1) * 8192;
            char* vb2 = lds + 16384 + (buf ^ 1) * 8192;
            gload_lds16(kb2 + o,        Kt + o);
            gload_lds16(kb2 + o + 4096, Kt + o + 4096);
            gload_lds16(vb2 + o,        Vt + o);
            gload_lds16(vb2 + o + 4096, Vt + o + 4096);
        }
        const char* ksb = lds + buf * 8192;
        const char* vtb = lds + 16384 + buf * 8192;

        f32x4 sc[4];
#pragma unroll
        for (int f = 0; f < 4; ++f) {
            s16x8 kf0 = *reinterpret_cast<const s16x8*>(ksb + swz(f * 16 + lr, kg * 16));
            s16x8 kf1 = *reinterpret_cast<const s16x8*>(ksb + swz(f * 16 + lr, 64 + kg * 16));
            f32x4 s = {};
            s = __builtin_amdgcn_mfma_f32_16x16x32_bf16(kf0, qf0, s, 0, 0, 0);
            s = __builtin_amdgcn_mfma_f32_16x16x32_bf16(kf1, qf1, s, 0, 0, 0);
            sc[f] = s;
        }
#pragma unroll
        for (int f = 0; f < 4; ++f)
#pragma unroll
            for (int j = 0; j < 4; ++j)
                sc[f][j] = __builtin_amdgcn_exp2f(sc[f][j]);
        if (t == qt) {
            const int qloc = w * 16 + lr;
#pragma unroll
            for (int f = 0; f < 4; ++f) {
                const int kc = f * 16 + kg * 4;
#pragma unroll
                for (int j = 0; j < 4; ++j)
                    if (kc + j > qloc) sc[f][j] = 0.f;
            }
        }
        float fs0 = 0.f, fs1 = 0.f;
#pragma unroll
        for (int f = 0; f < 4; ++f) {
            u32x2 pp;
            pp[0] = cvtpk(sc[f][0], sc[f][1]);
            pp[1] = cvtpk(sc[f][2], sc[f][3]);
            *reinterpret_cast<u32x2*>(psb + swz(lr, f * 32 + kg * 8)) = pp;
            const float s01 = sc[f][0] + sc[f][1], s23 = sc[f][2] + sc[f][3];
            if (f & 1) fs1 += s01 + s23; else fs0 += s01 + s23;
        }
        lp += fs0 + fs1;

        const s16x8 pf0 = *reinterpret_cast<const s16x8*>(psb + swz(lr, kg * 16));
        const s16x8 pf1 = *reinterpret_cast<const s16x8*>(psb + swz(lr, 64 + kg * 16));
#pragma unroll
        for (int db = 0; db < 4; ++db) {
            s16x8 vf0 = *reinterpret_cast<const s16x8*>(vtb + swz(db * 16 + lr, kg * 16));
            s16x8 vf1 = *reinterpret_cast<const s16x8*>(vtb + swz(db * 16 + lr, 64 + kg * 16));
            accO[db] = __builtin_amdgcn_mfma_f32_16x16x32_bf16(pf0, vf0, accO[db], 0, 0, 0);
            accO[db] = __builtin_amdgcn_mfma_f32_16x16x32_bf16(pf1, vf1, accO[db], 0, 0, 0);
        }
    }

    lp += __shfl_xor(lp, 16, 64);
    lp += __shfl_xor(lp, 32, 64);

    if (slot == 255) {
        float inv[4];
#pragma unroll
        for (int j = 0; j < 4; ++j)
            inv[j] = 1.0f / __shfl(lp, kg * 4 + j, 64);
#pragma unroll
        for (int db = 0; db < 4; ++db) {
            const int d = db * 16 + lr;
#pragma unroll
            for (int j = 0; j < 4; ++j) {
                const int s = qb + w * 16 + kg * 4 + j;
                AO[((size_t)(bb * SS + s)) * DM + hh * DK + d] = f2bf(accO[db][j] * inv[j]);
            }
        }
    } else {
        const int idx = bh * 32 + slot;
        u16* Od = Opart + (size_t)idx * 4096;
#pragma unroll
        for (int db = 0; db < 4; ++db) {
            const int d = db * 16 + lr;
#pragma unroll
            for (int j = 0; j < 4; ++j)
                Od[(w * 16 + kg * 4 + j) * 64 + d] = f2bf(accO[db][j]);
        }
        if (lane < 16)
            lpart[idx * 64 + w * 16 + lane] = lp;
    }
}

// combine partials for split q-tiles: AO = (O0+O1)/(l0+l1)
__global__ __launch_bounds__(256) void mha_combine(const u16* __restrict__ Opart,
                                                   const float* __restrict__ lpart,
                                                   u16* __restrict__ AO) {
    const int blk = blockIdx.x;          // 0..511
    const int bh = blk & 31, q = blk >> 5;
    const int qt = 16 + q;
    const int t = threadIdx.x;
    const int row = t >> 2, c0 = (t & 3) * 16;
    const int idx0 = bh * 32 + q * 2;
    const u16* O0 = Opart + (size_t)idx0 * 4096 + row * 64 + c0;
    const u16* O1 = O0 + 4096;
    const float l = lpart[idx0 * 64 + row] + lpart[(idx0 + 1) * 64 + row];
    const float inv = 1.0f / l;
    const int bb = bh >> 4, hh = bh & (NH - 1);
    const int s = qt * 64 + row;
    u16* dst = AO + ((size_t)(bb * SS + s)) * DM + hh * DK + c0;
#pragma unroll
    for (int h = 0; h < 2; ++h) {
        s16x8 a = *reinterpret_cast<const s16x8*>(O0 + h * 8);
        s16x8 b = *reinterpret_cast<const s16x8*>(O1 + h * 8);
        u16* ap = (u16*)&a; u16* bp = (u16*)&b;
        u16 ov[8];
#pragma unroll
    for (int i = 0; i < 8; ++i)
            ov[i] = f2bf((bf2f(ap[i]) + bf2f(bp[i])) * inv);
        *reinterpret_cast<ushort4*>(dst + h * 8) = *reinterpret_cast<ushort4*>(&ov[0]);
        *reinterpret_cast<ushort4*>(dst + h * 8 + 4) = *reinterpret_cast<ushort4*>(&ov[4]);
    }
}

extern "C" void kernel_launch(void* const* d_in, const int* in_sizes, int n_in,
                              void* d_out, int out_size, void* d_ws, size_t ws_size,
                              hipStream_t stream) {
    const float* x  = (const float*)d_in[0];
    const float* Wq = (const float*)d_in[2];
    const float* bq = (const float*)d_in[3];
    const float* Wk = (const float*)d_in[4];
    const float* bk = (const float*)d_in[5];
    const float* Wv = (const float*)d_in[6];
    const float* bv = (const float*)d_in[7];
    const float* Wo = (const float*)d_in[8];
    const float* bo = (const float*)d_in[9];
    float* out = (float*)d_out;

    char* ws = (char*)d_ws;
    u16* xb  = (u16*)(ws);                       // 8 MB (dead after gemm_qkv)
    u16* Wt  = (u16*)(ws + ((size_t)8  << 20));  // 8 MB (Wq,Wk,Wv dead after qkv; Wo^T kept)
    u16* qkv = (u16*)(ws + ((size_t)16 << 20));  // 24 MB: Q | K-swz tiles | V^T-swz tiles
    u16* AO  = (u16*)(ws + ((size_t)40 << 20));  // 8 MB
    u16*   Opart = (u16*)(ws);                       // 8 MB over xb
    float* lpart = (float*)(ws + ((size_t)8 << 20)); // 256 KB over Wq^T

    mha_prep<<<dim3(8192), dim3(256), 0, stream>>>(x, xb, Wq, Wk, Wv, Wo, Wt);
    mha_gemm_qkv<<<dim3(768), dim3(256), 0, stream>>>(xb, Wt, bq, bk, bv, qkv);
    mha_attn<<<dim3(1536), dim3(256), 0, stream>>>(qkv, qkv + (size_t)4194304, qkv + (size_t)8388608,
                                                   AO, Opart, lpart);
    mha_combine<<<dim3(512), dim3(256), 0, stream>>>(Opart, lpart, AO);
    mha_gemm_out<<<dim3(32, 8), dim3(256), 0, stream>>>(AO, Wt + (size_t)3 * DM * DM, bo, out);
}

// Round 18
// 102.696 us; speedup vs baseline: 1.0635x; 1.0082x over previous
//
#include <hip/hip_runtime.h>
#include <hip/hip_bf16.h>
#include <cstdint>
#include <cmath>

#define DM 1024
#define NH 16
#define DK 64
#define NB 2
#define SS 2048
#define MM (NB*SS)   // 4096 rows

typedef unsigned short u16;
typedef uint32_t u32;
typedef __attribute__((ext_vector_type(4))) float f32x4;
typedef __attribute__((ext_vector_type(8))) short s16x8;
typedef __attribute__((ext_vector_type(2))) uint32_t u32x2;

__device__ __forceinline__ u16 f2bf(float f) {
    __hip_bfloat16 h = __float2bfloat16(f);
    return __builtin_bit_cast(u16, h);
}
__device__ __forceinline__ float bf2f(u16 u) {
    u32 x = (u32)u << 16;
    return __builtin_bit_cast(float, x);
}

__device__ __forceinline__ u32 cvtpk(float a, float b) {
    u32 r;
    asm("v_cvt_pk_bf16_f32 %0, %1, %2" : "=v"(r) : "v"(a), "v"(b));
    return r;
}

__device__ __forceinline__ void gload_lds16(void* lds, const void* g) {
    __builtin_amdgcn_global_load_lds(
        (const __attribute__((address_space(1))) uint32_t*)g,
        (__attribute__((address_space(3))) uint32_t*)lds, 16, 0, 0);
}

// XOR-swizzled byte offset within a [rows][128B] LDS tile: 16B slot ^= row&7.
__device__ __forceinline__ int swz(int row, int cb) {
    return row * 128 + ((((cb) >> 4) ^ (row & 7)) << 4) + ((cb) & 15);
}

#define FENCE_BAR  do { __builtin_amdgcn_sched_barrier(0); \
                        __builtin_amdgcn_s_barrier();      \
                        __builtin_amdgcn_sched_barrier(0); } while (0)

// ---------------- prep: cast x -> bf16 AND transpose-cast W (one launch) ----------------
__global__ void mha_prep(const float* __restrict__ x, u16* __restrict__ xb,
                         const float* __restrict__ W0, const float* __restrict__ W1,
                         const float* __restrict__ W2, const float* __restrict__ W3,
                         u16* __restrict__ WtBase) {
    const int bid = blockIdx.x, tid = threadIdx.x;
    if (bid < 4096) {
        int i = (bid * 256 + tid) * 4;
        float4 v = *reinterpret_cast<const float4*>(x + i);
        ushort4 o;
        o.x = f2bf(v.x); o.y = f2bf(v.y); o.z = f2bf(v.z); o.w = f2bf(v.w);
        *reinterpret_cast<ushort4*>(xb + i) = o;
        return;
    }
    __shared__ float t[32][33];
    const int b2 = bid - 4096;
    const int mat = b2 >> 10, rem = b2 & 1023;
    const int cx = rem & 31, cy = rem >> 5;
    const float* W = (mat == 0) ? W0 : (mat == 1) ? W1 : (mat == 2) ? W2 : W3;
    u16* Wt = WtBase + (size_t)mat * DM * DM;
    const int c0 = cx * 32, r0 = cy * 32;
    const int tx = tid & 31, ty = tid >> 5;
#pragma unroll
    for (int i = ty; i < 32; i += 8)
        t[i][tx] = W[(size_t)(r0 + i) * DM + c0 + tx];
    __syncthreads();
#pragma unroll
    for (int i = ty; i < 32; i += 8)
        Wt[(size_t)(c0 + i) * DM + r0 + tx] = f2bf(t[tx][i]);
}

// ---------------- 128x128 tile bf16 MFMA GEMM main loop (r13-verified) ----------------
__device__ __forceinline__ void gemm_loop(const u16* __restrict__ A, const u16* __restrict__ Bt,
                                          int m0, int n0,
                                          u16 (*As)[64], u16 (*Bs)[64], f32x4 acc[4][4]) {
    const int tid = threadIdx.x;
    const int wave = tid >> 6, lane = tid & 63;
    const int lr = lane & 15, kg = lane >> 4;
    const int wr = wave >> 1, wc = wave & 1;

    for (int k0 = 0; k0 < DM; k0 += 64) {
        __syncthreads();
#pragma unroll
        for (int i = 0; i < 4; ++i) {
            const int o   = ((wave * 4 + i) * 64 + lane) * 16;
            const int row = o >> 7;
            const int kb  = o & 127;
            gload_lds16((char*)As + o, A  + (size_t)(m0 + row) * DM + k0 + (kb >> 1));
            gload_lds16((char*)Bs + o, Bt + (size_t)(n0 + row) * DM + k0 + (kb >> 1));
        }
        __syncthreads();
#pragma unroll
        for (int kk = 0; kk < 64; kk += 32) {
            s16x8 a[4], b[4];
#pragma unroll
            for (int m = 0; m < 4; ++m)
                a[m] = *reinterpret_cast<const s16x8*>(&As[wr * 64 + m * 16 + lr][kk + kg * 8]);
#pragma unroll
            for (int n = 0; n < 4; ++n)
                b[n] = *reinterpret_cast<const s16x8*>(&Bs[wc * 64 + n * 16 + lr][kk + kg * 8]);
#pragma unroll
            for (int m = 0; m < 4; ++m)
#pragma unroll
                for (int n = 0; n < 4; ++n)
                    acc[m][n] = __builtin_amdgcn_mfma_f32_16x16x32_bf16(a[m], b[n], acc[m][n], 0, 0, 0);
        }
    }
}

// QKV GEMM: r13-verified best config (42.7us)
__global__ __launch_bounds__(256, 2) void mha_gemm_qkv(const u16* __restrict__ xb, const u16* __restrict__ Wt,
                                                       const float* __restrict__ bq, const float* __restrict__ bk,
                                                       const float* __restrict__ bv, u16* __restrict__ qkv) {
    __shared__ __align__(16) char smem[32768];
    u16 (*As)[64] = reinterpret_cast<u16(*)[64]>(smem);
    u16 (*Bs)[64] = reinterpret_cast<u16(*)[64]>(smem + 16384);

    const int bid = blockIdx.x;
    const int j = bid & 7, r = bid >> 3;         // 768 = 8 XCDs x 96
    const int bx = j * 4 + (r & 3);
    const int by = (r >> 2) & 7;
    const int z  = r >> 5;                        // 0..2
    const int m0 = bx * 128, n0 = by * 128;

    const float* bias = (z == 0) ? bq : (z == 1) ? bk : bv;
    const float scale = (z == 0) ? 0.125f * 1.44269504088896f : 1.0f;
    u16* Cout = qkv + (size_t)z * MM * DM;

    f32x4 acc[4][4] = {};
    gemm_loop(xb, Wt + (size_t)z * DM * DM, m0, n0, As, Bs, acc);

    const int tid = threadIdx.x;
    const int wave = tid >> 6, lane = tid & 63;
    const int lr = lane & 15, kg = lane >> 4;
    const int wr = wave >> 1, wc = wave & 1;

    __syncthreads();
#pragma unroll
    for (int m = 0; m < 4; ++m)
#pragma unroll
        for (int n = 0; n < 4; ++n) {
            const int col = wc * 64 + n * 16 + lr;
            const float bv2 = bias[n0 + col];
#pragma unroll
            for (int j2 = 0; j2 < 4; ++j2) {
                const int row = wr * 64 + m * 16 + kg * 4 + j2;
                const float v = (acc[m][n][j2] + bv2) * scale;
                int imgoff;
                if (z == 0) {
                    imgoff = row * 256 + (col >> 6) * 128 + (col & 63) * 2;
                } else if (z == 1) {
                    imgoff = ((row >> 6) * 2 + (col >> 6)) * 8192 + swz(row & 63, (col & 63) * 2);
                } else {
                    imgoff = ((row >> 6) * 2 + (col >> 6)) * 8192
                           + swz(col & 63, ((row & 63) >> 1) * 4 + (row & 1) * 2);
                }
                *reinterpret_cast<u16*>(smem + imgoff) = f2bf(v);
            }
        }
    __syncthreads();
    const int bb = m0 >> 11, s0 = m0 & (SS - 1);
    const int kt0 = s0 >> 6, h0 = n0 >> 6;
#pragma unroll
    for (int it = 0; it < 8; ++it) {
        const int c = it * 256 + tid;
        const s16x8 v = *reinterpret_cast<const s16x8*>(smem + c * 16);
        u16* dst;
        if (z == 0) {
            const int srow = c >> 4, inrow = c & 15;
            const int hl = inrow >> 3, d0 = (inrow & 7) * 8;
            dst = Cout + (((size_t)(bb * NH + h0 + hl) * SS + (s0 + srow)) * DK) + d0;
        } else {
            const int quad = c >> 9, off = (c & 511) * 8;
            const int ktl = quad >> 1, hl = quad & 1;
            dst = Cout + ((size_t)(bb * NH + h0 + hl) * 32 + kt0 + ktl) * 4096 + off;
        }
        *reinterpret_cast<s16x8*>(dst) = v;
    }
}

// ---------------- gemm_out: counted-vmcnt dbuf (r15-verified) ----------------
__device__ __forceinline__ void gemm_loop_db(const u16* __restrict__ A, const u16* __restrict__ Bt,
                                             int m0, int n0, char* smem /*64KB*/, f32x4 acc[4][4]) {
    const int tid = threadIdx.x;
    const int wave = tid >> 6, lane = tid & 63;
    const int lr = lane & 15, kg = lane >> 4;
    const int wr = wave >> 1, wc = wave & 1;

    auto STAGE = [&](int buf, int k0) {
        char* As = smem + buf * 32768;
        char* Bs = As + 16384;
#pragma unroll
        for (int i = 0; i < 4; ++i) {
            const int o   = ((wave * 4 + i) * 64 + lane) * 16;
            const int row = o >> 7;
            const int kb  = o & 127;
            gload_lds16(As + o, A  + (size_t)(m0 + row) * DM + k0 + (kb >> 1));
            gload_lds16(Bs + o, Bt + (size_t)(n0 + row) * DM + k0 + (kb >> 1));
        }
    };

    STAGE(0, 0);
    for (int t = 0; t < 16; ++t) {
        if (t + 1 < 16) {
            STAGE((t + 1) & 1, (t + 1) * 64);
            asm volatile("s_waitcnt vmcnt(8)" ::: "memory");
        } else {
            asm volatile("s_waitcnt vmcnt(0)" ::: "memory");
        }
        FENCE_BAR;
        const u16 (*As)[64] = reinterpret_cast<const u16(*)[64]>(smem + (t & 1) * 32768);
        const u16 (*Bs)[64] = reinterpret_cast<const u16(*)[64]>(smem + (t & 1) * 32768 + 16384);
#pragma unroll
        for (int kk = 0; kk < 64; kk += 32) {
            s16x8 a[4], b[4];
#pragma unroll
            for (int m = 0; m < 4; ++m)
                a[m] = *reinterpret_cast<const s16x8*>(&As[wr * 64 + m * 16 + lr][kk + kg * 8]);
#pragma unroll
            for (int n = 0; n < 4; ++n)
                b[n] = *reinterpret_cast<const s16x8*>(&Bs[wc * 64 + n * 16 + lr][kk + kg * 8]);
#pragma unroll
            for (int m = 0; m < 4; ++m)
#pragma unroll
                for (int n = 0; n < 4; ++n)
                    acc[m][n] = __builtin_amdgcn_mfma_f32_16x16x32_bf16(a[m], b[n], acc[m][n], 0, 0, 0);
        }
        FENCE_BAR;
    }
}

__global__ __launch_bounds__(256, 2) void mha_gemm_out(const u16* __restrict__ AO, const u16* __restrict__ WoT,
                                                       const float* __restrict__ bo, float* __restrict__ out) {
    __shared__ __align__(16) char smem[65536];
    const int m0 = blockIdx.x * 128, n0 = blockIdx.y * 128;

    f32x4 acc[4][4] = {};
    gemm_loop_db(AO, WoT, m0, n0, smem, acc);

    const int tid = threadIdx.x;
    const int wave = tid >> 6, lane = tid & 63;
    const int lr = lane & 15, kg = lane >> 4;
    const int wr = wave >> 1, wc = wave & 1;
#pragma unroll
    for (int m = 0; m < 4; ++m)
#pragma unroll
        for (int n = 0; n < 4; ++n) {
            const int col = n0 + wc * 64 + n * 16 + lr;
            const float bv = bo[col];
#pragma unroll
            for (int j2 = 0; j2 < 4; ++j2) {
                const int row = m0 + wr * 64 + m * 16 + kg * 4 + j2;
                out[(size_t)row * DM + col] = acc[m][n][j2] + bv;
            }
        }
}

// ---------------- flash attention v11: QBLK=128, 8 waves ----------------
// r17 analysis: attn (~33us) was 4 blocks/CU (40KB LDS) with 16KB staging per
// 64 q-rows. QBLK=128 (512 thr): per-wave code identical (wave owns 16 q-rows);
// staging per q-row HALVES (1 gload/thread/tile); LDS 48KB -> 3 blocks x 8
// waves = 24 waves/CU (6/SIMD, up from 4). 24 jobs/bh, all <=16 iters, LPT.
__device__ const unsigned char JQT[24] = {
    7,15,15, 14,14, 6,13,13, 12,12, 5,11,11, 10,10, 4,9,9, 8,8, 3,2,1,0};
__device__ const unsigned char JKS[24] = {
    0,0,16, 0,15, 0,0,14, 0,13, 0,0,12, 0,11, 0,0,10, 0,9, 0,0,0,0};
__device__ const unsigned char JKL[24] = {
    16,16,16, 15,15, 14,14,14, 13,13, 12,12,12, 11,11, 10,10,10, 9,9, 8,6,4,2};
__device__ const unsigned char JSL[24] = {
    255,14,15, 12,13, 255,10,11, 8,9, 255,6,7, 4,5, 255,2,3, 0,1, 255,255,255,255};

__global__ __launch_bounds__(512, 4) void mha_attn(const u16* __restrict__ Qb, const u16* __restrict__ Kswz,
                                                   const u16* __restrict__ Vtswz, u16* __restrict__ AO,
                                                   u16* __restrict__ Opart, float* __restrict__ lpart) {
    // LDS: K dbuf 2x8KB @0 | V^T dbuf 2x8KB @16384 | Ps[8 waves][2KB] @32768
    __shared__ __align__(16) char lds[49152];

    const int bid = blockIdx.x;
    const int bh  = bid & 31;
    const int job = bid >> 5;                 // 0..23
    const int qt   = JQT[job];                // 128-row tile id, 0..15
    const int kst  = JKS[job];
    const int klen = JKL[job];
    const int slot = JSL[job];
    const int qb = qt * 128;

    const int tid = threadIdx.x, w = tid >> 6, lane = tid & 63;
    const int lr = lane & 15, kg = lane >> 4;

    const u16* Qh = Qb + (size_t)bh * SS * DK;
    const char* Ktiles = (const char*)(Kswz  + (size_t)bh * 32 * 4096);
    const char* Vtiles = (const char*)(Vtswz + (size_t)bh * 32 * 4096);
    const int bb = bh >> 4, hh = bh & (NH - 1);
    char* psb = lds + 32768 + w * 2048;
    const int o = tid * 16;                   // 512 thr x 16B = 8KB (one tile)

    const int qrow = qb + w * 16 + lr;
    const s16x8 qf0 = *reinterpret_cast<const s16x8*>(Qh + (size_t)qrow * DK + kg * 8);
    const s16x8 qf1 = *reinterpret_cast<const s16x8*>(Qh + (size_t)qrow * DK + 32 + kg * 8);
    f32x4 accO[4] = {};
    float lp = 0.f;

    const int kend = kst + klen;
    gload_lds16(lds + o,         Ktiles + kst * 8192 + o);
    gload_lds16(lds + 16384 + o, Vtiles + kst * 8192 + o);

    for (int t = kst; t < kend; ++t) {
        const int buf = (t - kst) & 1;
        asm volatile("s_waitcnt vmcnt(0)" ::: "memory");
        __syncthreads();
        if (t + 1 < kend) {
            gload_lds16(lds + (buf ^ 1) * 8192 + o,         Ktiles + (t + 1) * 8192 + o);
            gload_lds16(lds + 16384 + (buf ^ 1) * 8192 + o, Vtiles + (t + 1) * 8192 + o);
        }
        const char* ksb = lds + buf * 8192;
        const char* vtb = lds + 16384 + buf * 8192;
        const int kb = t * 64;

        // swapped QK^T: lane holds P[q=lr][k=f*16+kg*4+j]
        f32x4 sc[4];
#pragma unroll
        for (int f = 0; f < 4; ++f) {
            s16x8 kf0 = *reinterpret_cast<const s16x8*>(ksb + swz(f * 16 + lr, kg * 16));
            s16x8 kf1 = *reinterpret_cast<const s16x8*>(ksb + swz(f * 16 + lr, 64 + kg * 16));
            f32x4 s = {};
            s = __builtin_amdgcn_mfma_f32_16x16x32_bf16(kf0, qf0, s, 0, 0, 0);
            s = __builtin_amdgcn_mfma_f32_16x16x32_bf16(kf1, qf1, s, 0, 0, 0);
            sc[f] = s;
        }
#pragma unroll
        for (int f = 0; f < 4; ++f)
#pragma unroll
            for (int j = 0; j < 4; ++j)
                sc[f][j] = __builtin_amdgcn_exp2f(sc[f][j]);
        if (kb + 63 > qb + w * 16) {      // wave-uniform: k-tile overlaps causal frontier
            const int qg = qb + w * 16 + lr;
#pragma unroll
            for (int f = 0; f < 4; ++f) {
                const int kc = kb + f * 16 + kg * 4;
#pragma unroll
                for (int j = 0; j < 4; ++j)
                    if (kc + j > qg) sc[f][j] = 0.f;
            }
        }
        float fs0 = 0.f, fs1 = 0.f;
#pragma unroll
        for (int f = 0; f < 4; ++f) {
            u32x2 pp;
            pp[0] = cvtpk(sc[f][0], sc[f][1]);
            pp[1] = cvtpk(sc[f][2], sc[f][3]);
            *reinterpret_cast<u32x2*>(psb + swz(lr, f * 32 + kg * 8)) = pp;
            const float s01 = sc[f][0] + sc[f][1], s23 = sc[f][2] + sc[f][3];
            if (f & 1) fs1 += s01 + s23; else fs0 += s01 + s23;
        }
        lp += fs0 + fs1;

        const s16x8 pf0 = *reinterpret_cast<const s16x8*>(psb + swz(lr, kg * 16));
        const s16x8 pf1 = *reinterpret_cast<const s16x8*>(psb + swz(lr, 64 + kg * 16));
#pragma unroll
        for (int db = 0; db < 4; ++db) {
            s16x8 vf0 = *reinterpret_cast<const s16x8*>(vtb + swz(db * 16 + lr, kg * 16));
            s16x8 vf1 = *reinterpret_cast<const s16x8*>(vtb + swz(db * 16 + lr, 64 + kg * 16));
            accO[db] = __builtin_amdgcn_mfma_f32_16x16x32_bf16(pf0, vf0, accO[db], 0, 0, 0);
            accO[db] = __builtin_amdgcn_mfma_f32_16x16x32_bf16(pf1, vf1, accO[db], 0, 0, 0);
        }
    }

    lp += __shfl_xor(lp, 16, 64);
    lp += __shfl_xor(lp, 32, 64);

    if (slot == 255) {
        float inv[4];
#pragma unroll
        for (int j = 0; j < 4; ++j)
            inv[j] = 1.0f / __shfl(lp, kg * 4 + j, 64);
#pragma unroll
        for (int db = 0; db < 4; ++db) {
            const int d = db * 16 + lr;
#pragma unroll
            for (int j = 0; j < 4; ++j) {
                const int s = qb + w * 16 + kg * 4 + j;
                AO[((size_t)(bb * SS + s)) * DM + hh * DK + d] = f2bf(accO[db][j] * inv[j]);
            }
        }
    } else {
        const int idx = bh * 16 + slot;
        u16* Od = Opart + (size_t)idx * 8192;
#pragma unroll
        for (int db = 0; db < 4; ++db) {
            const int d = db * 16 + lr;
#pragma unroll
            for (int j = 0; j < 4; ++j)
                Od[(w * 16 + kg * 4 + j) * 64 + d] = f2bf(accO[db][j]);
        }
        if (lane < 16)
            lpart[idx * 128 + w * 16 + lane] = lp;
    }
}

// combine partials for split q-tiles (qt 8..15): AO = (O0+O1)/(l0+l1)
__global__ __launch_bounds__(256) void mha_combine(const u16* __restrict__ Opart,
                                                   const float* __restrict__ lpart,
                                                   u16* __restrict__ AO) {
    const int blk = blockIdx.x;          // 0..255
    const int bh = blk & 31, q = blk >> 5;   // q 0..7
    const int qt = 8 + q;
    const int t = threadIdx.x;
    const int row = t >> 1, c0 = (t & 1) * 32;   // 128 rows x 2 half-rows
    const int idx0 = bh * 16 + q * 2;
    const u16* O0 = Opart + (size_t)idx0 * 8192 + row * 64 + c0;
    const u16* O1 = O0 + 8192;
    const float l = lpart[idx0 * 128 + row] + lpart[(idx0 + 1) * 128 + row];
    const float inv = 1.0f / l;
    const int bb = bh >> 4, hh = bh & (NH - 1);
    const int s = qt * 128 + row;
    u16* dst = AO + ((size_t)(bb * SS + s)) * DM + hh * DK + c0;
#pragma unroll
    for (int h = 0; h < 4; ++h) {
        s16x8 a = *reinterpret_cast<const s16x8*>(O0 + h * 8);
        s16x8 b = *reinterpret_cast<const s16x8*>(O1 + h * 8);
        u16* ap = (u16*)&a; u16* bp = (u16*)&b;
        u16 ov[8];
#pragma unroll
        for (int i = 0; i < 8; ++i)
            ov[i] = f2bf((bf2f(ap[i]) + bf2f(bp[i])) * inv);
        *reinterpret_cast<ushort4*>(dst + h * 8) = *reinterpret_cast<ushort4*>(&ov[0]);
        *reinterpret_cast<ushort4*>(dst + h * 8 + 4) = *reinterpret_cast<ushort4*>(&ov[4]);
    }
}

extern "C" void kernel_launch(void* const* d_in, const int* in_sizes, int n_in,
                              void* d_out, int out_size, void* d_ws, size_t ws_size,
                              hipStream_t stream) {
    const float* x  = (const float*)d_in[0];
    const float* Wq = (const float*)d_in[2];
    const float* bq = (const float*)d_in[3];
    const float* Wk = (const float*)d_in[4];
    const float* bk = (const float*)d_in[5];
    const float* Wv = (const float*)d_in[6];
    const float* bv = (const float*)d_in[7];
    const float* Wo = (const float*)d_in[8];
    const float* bo = (const float*)d_in[9];
    float* out = (float*)d_out;

    char* ws = (char*)d_ws;
    u16* xb  = (u16*)(ws);                       // 8 MB (dead after gemm_qkv)
    u16* Wt  = (u16*)(ws + ((size_t)8  << 20));  // 8 MB
    u16* qkv = (u16*)(ws + ((size_t)16 << 20));  // 24 MB: Q | K-swz tiles | V^T-swz tiles
    u16* AO  = (u16*)(ws + ((size_t)40 << 20));  // 8 MB
    u16*   Opart = (u16*)(ws);                       // 8 MB over xb (512 slots x 16KB)
    float* lpart = (float*)(ws + ((size_t)8 << 20)); // 256 KB over Wq^T

    mha_prep<<<dim3(8192), dim3(256), 0, stream>>>(x, xb, Wq, Wk, Wv, Wo, Wt);
    mha_gemm_qkv<<<dim3(768), dim3(256), 0, stream>>>(xb, Wt, bq, bk, bv, qkv);
    mha_attn<<<dim3(768), dim3(512), 0, stream>>>(qkv, qkv + (size_t)4194304, qkv + (size_t)8388608,
                                                  AO, Opart, lpart);
    mha_combine<<<dim3(256), dim3(256), 0, stream>>>(Opart, lpart, AO);
    mha_gemm_out<<<dim3(32, 8), dim3(256), 0, stream>>>(AO, Wt + (size_t)3 * DM * DM, bo, out);
}

// Round 19
// 102.152 us; speedup vs baseline: 1.0691x; 1.0053x over previous
//
#include <hip/hip_runtime.h>
#include <hip/hip_bf16.h>
#include <cstdint>
#include <cmath>

#define DM 1024
#define NH 16
#define DK 64
#define NB 2
#define SS 2048
#define MM (NB*SS)   // 4096 rows

typedef unsigned short u16;
typedef uint32_t u32;
typedef __attribute__((ext_vector_type(4))) float f32x4;
typedef __attribute__((ext_vector_type(8))) short s16x8;
typedef __attribute__((ext_vector_type(2))) uint32_t u32x2;

__device__ __forceinline__ u16 f2bf(float f) {
    __hip_bfloat16 h = __float2bfloat16(f);
    return __builtin_bit_cast(u16, h);
}
__device__ __forceinline__ float bf2f(u16 u) {
    u32 x = (u32)u << 16;
    return __builtin_bit_cast(float, x);
}

__device__ __forceinline__ u32 cvtpk(float a, float b) {
    u32 r;
    asm("v_cvt_pk_bf16_f32 %0, %1, %2" : "=v"(r) : "v"(a), "v"(b));
    return r;
}

__device__ __forceinline__ void gload_lds16(void* lds, const void* g) {
    __builtin_amdgcn_global_load_lds(
        (const __attribute__((address_space(1))) uint32_t*)g,
        (__attribute__((address_space(3))) uint32_t*)lds, 16, 0, 0);
}

// XOR-swizzled byte offset within a [rows][128B] LDS tile: 16B slot ^= row&7.
__device__ __forceinline__ int swz(int row, int cb) {
    return row * 128 + ((((cb) >> 4) ^ (row & 7)) << 4) + ((cb) & 15);
}

#define FENCE_BAR  do { __builtin_amdgcn_sched_barrier(0); \
                        __builtin_amdgcn_s_barrier();      \
                        __builtin_amdgcn_sched_barrier(0); } while (0)

// ---------------- prep: cast x -> bf16 AND transpose-cast W (one launch) ----------------
__global__ void mha_prep(const float* __restrict__ x, u16* __restrict__ xb,
                         const float* __restrict__ W0, const float* __restrict__ W1,
                         const float* __restrict__ W2, const float* __restrict__ W3,
                         u16* __restrict__ WtBase) {
    const int bid = blockIdx.x, tid = threadIdx.x;
    if (bid < 4096) {
        int i = (bid * 256 + tid) * 4;
        float4 v = *reinterpret_cast<const float4*>(x + i);
        ushort4 o;
        o.x = f2bf(v.x); o.y = f2bf(v.y); o.z = f2bf(v.z); o.w = f2bf(v.w);
        *reinterpret_cast<ushort4*>(xb + i) = o;
        return;
    }
    __shared__ float t[32][33];
    const int b2 = bid - 4096;
    const int mat = b2 >> 10, rem = b2 & 1023;
    const int cx = rem & 31, cy = rem >> 5;
    const float* W = (mat == 0) ? W0 : (mat == 1) ? W1 : (mat == 2) ? W2 : W3;
    u16* Wt = WtBase + (size_t)mat * DM * DM;
    const int c0 = cx * 32, r0 = cy * 32;
    const int tx = tid & 31, ty = tid >> 5;
#pragma unroll
    for (int i = ty; i < 32; i += 8)
        t[i][tx] = W[(size_t)(r0 + i) * DM + c0 + tx];
    __syncthreads();
#pragma unroll
    for (int i = ty; i < 32; i += 8)
        Wt[(size_t)(c0 + i) * DM + r0 + tx] = f2bf(t[tx][i]);
}

// ---------------- QKV GEMM v2: 128x192 tiles, 512 balanced blocks, counted-vmcnt dbuf ----------------
// r15 post-mortem: the pipeline was fine; 768 blocks at 2/CU left a 256-block
// tail at 1/CU. Fix: fused-N 3072 tiled 128x192 -> 32x16 = 512 blocks = exactly
// 2/CU, one round. LDS 80KB (A 2x16KB + B 2x24KB); vmcnt(10) gate (10 loads/
// thread/tile, in-order retire); T2 pre-swizzled sources (r16-verified);
// never drain mid-loop. Direct-scatter epilogue (r11/r12: staging-neutral).
__global__ __launch_bounds__(256, 2) void mha_gemm_qkv(const u16* __restrict__ xb, const u16* __restrict__ Wt,
                                                       const float* __restrict__ bq, const float* __restrict__ bk,
                                                       const float* __restrict__ bv, u16* __restrict__ qkv) {
    __shared__ __align__(16) char smem[81920];   // A[2][128][64] @0, B[2][192][64] @32768

    const int bid = blockIdx.x;
    const int bx = bid & 31, by = bid >> 5;      // 32 x 16
    const int m0 = bx * 128, n0g = by * 192;     // n0g in fused 0..3071

    const int tid = threadIdx.x;
    const int wave = tid >> 6, lane = tid & 63;
    const int lr = lane & 15, kg = lane >> 4;
    const int wr = wave >> 1, wc = wave & 1;     // wave owns 64x96

    auto STAGE = [&](int buf, int kt) {
#pragma unroll
        for (int i = 0; i < 4; ++i) {            // A: 16KB
            const int o = tid * 16 + i * 4096;
            const int r = o >> 7, slot = (o >> 4) & 7;
            gload_lds16(smem + buf * 16384 + o,
                        xb + (size_t)(m0 + r) * DM + kt * 64 + ((slot ^ (r & 7)) << 3));
        }
#pragma unroll
        for (int i = 0; i < 6; ++i) {            // B: 24KB (Wt rows n0g..n0g+191, fused)
            const int o = tid * 16 + i * 4096;
            const int r = o >> 7, slot = (o >> 4) & 7;
            gload_lds16(smem + 32768 + buf * 24576 + o,
                        Wt + (size_t)(n0g + r) * DM + kt * 64 + ((slot ^ (r & 7)) << 3));
        }
    };

    f32x4 acc[4][6] = {};
    STAGE(0, 0);
    for (int t = 0; t < 16; ++t) {
        if (t + 1 < 16) {
            STAGE((t + 1) & 1, t + 1);
            asm volatile("s_waitcnt vmcnt(10)" ::: "memory");   // tile t's 10 loads done
        } else {
            asm volatile("s_waitcnt vmcnt(0)" ::: "memory");
        }
        FENCE_BAR;
        const char* Ab = smem + (t & 1) * 16384;
        const char* Bb = smem + 32768 + (t & 1) * 24576;
#pragma unroll
        for (int ks = 0; ks < 2; ++ks) {
            s16x8 a[4], b[6];
#pragma unroll
            for (int m = 0; m < 4; ++m)
                a[m] = *reinterpret_cast<const s16x8*>(Ab + swz(wr * 64 + m * 16 + lr, ks * 64 + kg * 16));
#pragma unroll
            for (int n = 0; n < 6; ++n)
                b[n] = *reinterpret_cast<const s16x8*>(Bb + swz(wc * 96 + n * 16 + lr, ks * 64 + kg * 16));
#pragma unroll
            for (int m = 0; m < 4; ++m)
#pragma unroll
                for (int n = 0; n < 6; ++n)
                    acc[m][n] = __builtin_amdgcn_mfma_f32_16x16x32_bf16(a[m], b[n], acc[m][n], 0, 0, 0);
        }
        FENCE_BAR;
    }

    // direct-scatter epilogue; z resolved per 16-lane run (runs never cross 1024)
#pragma unroll
    for (int m = 0; m < 4; ++m)
#pragma unroll
        for (int n = 0; n < 6; ++n) {
            const int colg = n0g + wc * 96 + n * 16 + lr;    // 0..3071
            const int z = colg >> 10, coll = colg & 1023;
            const int h = coll >> 6, d = coll & 63;
            const float bv2 = ((z == 0) ? bq : (z == 1) ? bk : bv)[coll];
            const float scale = (z == 0) ? 0.125f * 1.44269504088896f : 1.0f;
            u16* Cout = qkv + (size_t)z * MM * DM;
#pragma unroll
            for (int j = 0; j < 4; ++j) {
                const int row = m0 + wr * 64 + m * 16 + kg * 4 + j;
                const int bb = row >> 11, s = row & (SS - 1);
                const float v = (acc[m][n][j] + bv2) * scale;
                if (z == 0) {
                    Cout[(((size_t)(bb * NH + h) * SS + s) * DK) + d] = f2bf(v);
                } else {
                    const int kt = s >> 6, r = s & 63;
                    const size_t tb = ((size_t)(bb * NH + h) * 32 + kt) * 4096;
                    const int bo = (z == 1) ? swz(r, d * 2)
                                            : swz(d, (r >> 1) * 4 + (r & 1) * 2);
                    Cout[tb + (bo >> 1)] = f2bf(v);
                }
            }
        }
}

// ---------------- gemm_out: counted-vmcnt dbuf (r15-verified) ----------------
__device__ __forceinline__ void gemm_loop_db(const u16* __restrict__ A, const u16* __restrict__ Bt,
                                             int m0, int n0, char* smem /*64KB*/, f32x4 acc[4][4]) {
    const int tid = threadIdx.x;
    const int wave = tid >> 6, lane = tid & 63;
    const int lr = lane & 15, kg = lane >> 4;
    const int wr = wave >> 1, wc = wave & 1;

    auto STAGE = [&](int buf, int k0) {
        char* As = smem + buf * 32768;
        char* Bs = As + 16384;
#pragma unroll
        for (int i = 0; i < 4; ++i) {
            const int o   = ((wave * 4 + i) * 64 + lane) * 16;
            const int row = o >> 7;
            const int kb  = o & 127;
            gload_lds16(As + o, A  + (size_t)(m0 + row) * DM + k0 + (kb >> 1));
            gload_lds16(Bs + o, Bt + (size_t)(n0 + row) * DM + k0 + (kb >> 1));
        }
    };

    STAGE(0, 0);
    for (int t = 0; t < 16; ++t) {
        if (t + 1 < 16) {
            STAGE((t + 1) & 1, (t + 1) * 64);
            asm volatile("s_waitcnt vmcnt(8)" ::: "memory");
        } else {
            asm volatile("s_waitcnt vmcnt(0)" ::: "memory");
        }
        FENCE_BAR;
        const u16 (*As)[64] = reinterpret_cast<const u16(*)[64]>(smem + (t & 1) * 32768);
        const u16 (*Bs)[64] = reinterpret_cast<const u16(*)[64]>(smem + (t & 1) * 32768 + 16384);
#pragma unroll
        for (int kk = 0; kk < 64; kk += 32) {
            s16x8 a[4], b[4];
#pragma unroll
            for (int m = 0; m < 4; ++m)
                a[m] = *reinterpret_cast<const s16x8*>(&As[wr * 64 + m * 16 + lr][kk + kg * 8]);
#pragma unroll
            for (int n = 0; n < 4; ++n)
                b[n] = *reinterpret_cast<const s16x8*>(&Bs[wc * 64 + n * 16 + lr][kk + kg * 8]);
#pragma unroll
            for (int m = 0; m < 4; ++m)
#pragma unroll
                for (int n = 0; n < 4; ++n)
                    acc[m][n] = __builtin_amdgcn_mfma_f32_16x16x32_bf16(a[m], b[n], acc[m][n], 0, 0, 0);
        }
        FENCE_BAR;
    }
}

__global__ __launch_bounds__(256, 2) void mha_gemm_out(const u16* __restrict__ AO, const u16* __restrict__ WoT,
                                                       const float* __restrict__ bo, float* __restrict__ out) {
    __shared__ __align__(16) char smem[65536];
    const int m0 = blockIdx.x * 128, n0 = blockIdx.y * 128;

    f32x4 acc[4][4] = {};
    gemm_loop_db(AO, WoT, m0, n0, smem, acc);

    const int tid = threadIdx.x;
    const int wave = tid >> 6, lane = tid & 63;
    const int lr = lane & 15, kg = lane >> 4;
    const int wr = wave >> 1, wc = wave & 1;
#pragma unroll
    for (int m = 0; m < 4; ++m)
#pragma unroll
        for (int n = 0; n < 4; ++n) {
            const int col = n0 + wc * 64 + n * 16 + lr;
            const float bv = bo[col];
#pragma unroll
            for (int j2 = 0; j2 < 4; ++j2) {
                const int row = m0 + wr * 64 + m * 16 + kg * 4 + j2;
                out[(size_t)row * DM + col] = acc[m][n][j2] + bv;
            }
        }
}

// ---------------- flash attention v11 (r18): QBLK=128, 8 waves ----------------
__device__ const unsigned char JQT[24] = {
    7,15,15, 14,14, 6,13,13, 12,12, 5,11,11, 10,10, 4,9,9, 8,8, 3,2,1,0};
__device__ const unsigned char JKS[24] = {
    0,0,16, 0,15, 0,0,14, 0,13, 0,0,12, 0,11, 0,0,10, 0,9, 0,0,0,0};
__device__ const unsigned char JKL[24] = {
    16,16,16, 15,15, 14,14,14, 13,13, 12,12,12, 11,11, 10,10,10, 9,9, 8,6,4,2};
__device__ const unsigned char JSL[24] = {
    255,14,15, 12,13, 255,10,11, 8,9, 255,6,7, 4,5, 255,2,3, 0,1, 255,255,255,255};

__global__ __launch_bounds__(512, 4) void mha_attn(const u16* __restrict__ Qb, const u16* __restrict__ Kswz,
                                                   const u16* __restrict__ Vtswz, u16* __restrict__ AO,
                                                   u16* __restrict__ Opart, float* __restrict__ lpart) {
    __shared__ __align__(16) char lds[49152];

    const int bid = blockIdx.x;
    const int bh  = bid & 31;
    const int job = bid >> 5;
    const int qt   = JQT[job];
    const int kst  = JKS[job];
    const int klen = JKL[job];
    const int slot = JSL[job];
    const int qb = qt * 128;

    const int tid = threadIdx.x, w = tid >> 6, lane = tid & 63;
    const int lr = lane & 15, kg = lane >> 4;

    const u16* Qh = Qb + (size_t)bh * SS * DK;
    const char* Ktiles = (const char*)(Kswz  + (size_t)bh * 32 * 4096);
    const char* Vtiles = (const char*)(Vtswz + (size_t)bh * 32 * 4096);
    const int bb = bh >> 4, hh = bh & (NH - 1);
    char* psb = lds + 32768 + w * 2048;
    const int o = tid * 16;

    const int qrow = qb + w * 16 + lr;
    const s16x8 qf0 = *reinterpret_cast<const s16x8*>(Qh + (size_t)qrow * DK + kg * 8);
    const s16x8 qf1 = *reinterpret_cast<const s16x8*>(Qh + (size_t)qrow * DK + 32 + kg * 8);
    f32x4 accO[4] = {};
    float lp = 0.f;

    const int kend = kst + klen;
    gload_lds16(lds + o,         Ktiles + kst * 8192 + o);
    gload_lds16(lds + 16384 + o, Vtiles + kst * 8192 + o);

    for (int t = kst; t < kend; ++t) {
        const int buf = (t - kst) & 1;
        asm volatile("s_waitcnt vmcnt(0)" ::: "memory");
        __syncthreads();
        if (t + 1 < kend) {
            gload_lds16(lds + (buf ^ 1) * 8192 + o,         Ktiles + (t + 1) * 8192 + o);
            gload_lds16(lds + 16384 + (buf ^ 1) * 8192 + o, Vtiles + (t + 1) * 8192 + o);
        }
        const char* ksb = lds + buf * 8192;
        const char* vtb = lds + 16384 + buf * 8192;
        const int kb = t * 64;

        f32x4 sc[4];
#pragma unroll
        for (int f = 0; f < 4; ++f) {
            s16x8 kf0 = *reinterpret_cast<const s16x8*>(ksb + swz(f * 16 + lr, kg * 16));
            s16x8 kf1 = *reinterpret_cast<const s16x8*>(ksb + swz(f * 16 + lr, 64 + kg * 16));
            f32x4 s = {};
            s = __builtin_amdgcn_mfma_f32_16x16x32_bf16(kf0, qf0, s, 0, 0, 0);
            s = __builtin_amdgcn_mfma_f32_16x16x32_bf16(kf1, qf1, s, 0, 0, 0);
            sc[f] = s;
        }
#pragma unroll
        for (int f = 0; f < 4; ++f)
#pragma unroll
            for (int j = 0; j < 4; ++j)
                sc[f][j] = __builtin_amdgcn_exp2f(sc[f][j]);
        if (kb + 63 > qb + w * 16) {
            const int qg = qb + w * 16 + lr;
#pragma unroll
            for (int f = 0; f < 4; ++f) {
                const int kc = kb + f * 16 + kg * 4;
#pragma unroll
                for (int j = 0; j < 4; ++j)
                    if (kc + j > qg) sc[f][j] = 0.f;
            }
        }
        float fs0 = 0.f, fs1 = 0.f;
#pragma unroll
        for (int f = 0; f < 4; ++f) {
            u32x2 pp;
            pp[0] = cvtpk(sc[f][0], sc[f][1]);
            pp[1] = cvtpk(sc[f][2], sc[f][3]);
            *reinterpret_cast<u32x2*>(psb + swz(lr, f * 32 + kg * 8)) = pp;
            const float s01 = sc[f][0] + sc[f][1], s23 = sc[f][2] + sc[f][3];
            if (f & 1) fs1 += s01 + s23; else fs0 += s01 + s23;
        }
        lp += fs0 + fs1;

        const s16x8 pf0 = *reinterpret_cast<const s16x8*>(psb + swz(lr, kg * 16));
        const s16x8 pf1 = *reinterpret_cast<const s16x8*>(psb + swz(lr, 64 + kg * 16));
#pragma unroll
        for (int db = 0; db < 4; ++db) {
            s16x8 vf0 = *reinterpret_cast<const s16x8*>(vtb + swz(db * 16 + lr, kg * 16));
            s16x8 vf1 = *reinterpret_cast<const s16x8*>(vtb + swz(db * 16 + lr, 64 + kg * 16));
            accO[db] = __builtin_amdgcn_mfma_f32_16x16x32_bf16(pf0, vf0, accO[db], 0, 0, 0);
            accO[db] = __builtin_amdgcn_mfma_f32_16x16x32_bf16(pf1, vf1, accO[db], 0, 0, 0);
        }
    }

    lp += __shfl_xor(lp, 16, 64);
    lp += __shfl_xor(lp, 32, 64);

    if (slot == 255) {
        float inv[4];
#pragma unroll
        for (int j = 0; j < 4; ++j)
            inv[j] = 1.0f / __shfl(lp, kg * 4 + j, 64);
#pragma unroll
        for (int db = 0; db < 4; ++db) {
            const int d = db * 16 + lr;
#pragma unroll
            for (int j = 0; j < 4; ++j) {
                const int s = qb + w * 16 + kg * 4 + j;
                AO[((size_t)(bb * SS + s)) * DM + hh * DK + d] = f2bf(accO[db][j] * inv[j]);
            }
        }
    } else {
        const int idx = bh * 16 + slot;
        u16* Od = Opart + (size_t)idx * 8192;
#pragma unroll
        for (int db = 0; db < 4; ++db) {
            const int d = db * 16 + lr;
#pragma unroll
            for (int j = 0; j < 4; ++j)
                Od[(w * 16 + kg * 4 + j) * 64 + d] = f2bf(accO[db][j]);
        }
        if (lane < 16)
            lpart[idx * 128 + w * 16 + lane] = lp;
    }
}

// combine partials for split q-tiles (qt 8..15): AO = (O0+O1)/(l0+l1)
__global__ __launch_bounds__(256) void mha_combine(const u16* __restrict__ Opart,
                                                   const float* __restrict__ lpart,
                                                   u16* __restrict__ AO) {
    const int blk = blockIdx.x;          // 0..255
    const int bh = blk & 31, q = blk >> 5;
    const int qt = 8 + q;
    const int t = threadIdx.x;
    const int row = t >> 1, c0 = (t & 1) * 32;
    const int idx0 = bh * 16 + q * 2;
    const u16* O0 = Opart + (size_t)idx0 * 8192 + row * 64 + c0;
    const u16* O1 = O0 + 8192;
    const float l = lpart[idx0 * 128 + row] + lpart[(idx0 + 1) * 128 + row];
    const float inv = 1.0f / l;
    const int bb = bh >> 4, hh = bh & (NH - 1);
    const int s = qt * 128 + row;
    u16* dst = AO + ((size_t)(bb * SS + s)) * DM + hh * DK + c0;
#pragma unroll
    for (int h = 0; h < 4; ++h) {
        s16x8 a = *reinterpret_cast<const s16x8*>(O0 + h * 8);
        s16x8 b = *reinterpret_cast<const s16x8*>(O1 + h * 8);
        u16* ap = (u16*)&a; u16* bp = (u16*)&b;
        u16 ov[8];
#pragma unroll
        for (int i = 0; i < 8; ++i)
            ov[i] = f2bf((bf2f(ap[i]) + bf2f(bp[i])) * inv);
        *reinterpret_cast<ushort4*>(dst + h * 8) = *reinterpret_cast<ushort4*>(&ov[0]);
        *reinterpret_cast<ushort4*>(dst + h * 8 + 4) = *reinterpret_cast<ushort4*>(&ov[4]);
    }
}

extern "C" void kernel_launch(void* const* d_in, const int* in_sizes, int n_in,
                              void* d_out, int out_size, void* d_ws, size_t ws_size,
                              hipStream_t stream) {
    const float* x  = (const float*)d_in[0];
    const float* Wq = (const float*)d_in[2];
    const float* bq = (const float*)d_in[3];
    const float* Wk = (const float*)d_in[4];
    const float* bk = (const float*)d_in[5];
    const float* Wv = (const float*)d_in[6];
    const float* bv = (const float*)d_in[7];
    const float* Wo = (const float*)d_in[8];
    const float* bo = (const float*)d_in[9];
    float* out = (float*)d_out;

    char* ws = (char*)d_ws;
    u16* xb  = (u16*)(ws);                       // 8 MB (dead after gemm_qkv)
    u16* Wt  = (u16*)(ws + ((size_t)8  << 20));  // 8 MB: Wq^T|Wk^T|Wv^T|Wo^T (rows 0..4095)
    u16* qkv = (u16*)(ws + ((size_t)16 << 20));  // 24 MB: Q | K-swz tiles | V^T-swz tiles
    u16* AO  = (u16*)(ws + ((size_t)40 << 20));  // 8 MB
    u16*   Opart = (u16*)(ws);                       // 8 MB over xb
    float* lpart = (float*)(ws + ((size_t)8 << 20)); // 256 KB over Wq^T

    mha_prep<<<dim3(8192), dim3(256), 0, stream>>>(x, xb, Wq, Wk, Wv, Wo, Wt);
    mha_gemm_qkv<<<dim3(512), dim3(256), 0, stream>>>(xb, Wt, bq, bk, bv, qkv);
    mha_attn<<<dim3(768), dim3(512), 0, stream>>>(qkv, qkv + (size_t)4194304, qkv + (size_t)8388608,
                                                  AO, Opart, lpart);
    mha_combine<<<dim3(256), dim3(256), 0, stream>>>(Opart, lpart, AO);
    mha_gemm_out<<<dim3(32, 8), dim3(256), 0, stream>>>(AO, Wt + (size_t)3 * DM * DM, bo, out);
}

// Round 20
// 98.308 us; speedup vs baseline: 1.1109x; 1.0391x over previous
//
#include <hip/hip_runtime.h>
#include <hip/hip_bf16.h>
#include <cstdint>
#include <cmath>

#define DM 1024
#define NH 16
#define DK 64
#define NB 2
#define SS 2048
#define MM (NB*SS)   // 4096 rows

typedef unsigned short u16;
typedef uint32_t u32;
typedef __attribute__((ext_vector_type(4))) float f32x4;
typedef __attribute__((ext_vector_type(8))) short s16x8;
typedef __attribute__((ext_vector_type(2))) uint32_t u32x2;

__device__ __forceinline__ u16 f2bf(float f) {
    __hip_bfloat16 h = __float2bfloat16(f);
    return __builtin_bit_cast(u16, h);
}
__device__ __forceinline__ float bf2f(u16 u) {
    u32 x = (u32)u << 16;
    return __builtin_bit_cast(float, x);
}

__device__ __forceinline__ u32 cvtpk(float a, float b) {
    u32 r;
    asm("v_cvt_pk_bf16_f32 %0, %1, %2" : "=v"(r) : "v"(a), "v"(b));
    return r;
}

__device__ __forceinline__ void gload_lds16(void* lds, const void* g) {
    __builtin_amdgcn_global_load_lds(
        (const __attribute__((address_space(1))) uint32_t*)g,
        (__attribute__((address_space(3))) uint32_t*)lds, 16, 0, 0);
}

// XOR-swizzled byte offset within a [rows][128B] LDS tile: 16B slot ^= row&7.
__device__ __forceinline__ int swz(int row, int cb) {
    return row * 128 + ((((cb) >> 4) ^ (row & 7)) << 4) + ((cb) & 15);
}

#define FENCE_BAR  do { __builtin_amdgcn_sched_barrier(0); \
                        __builtin_amdgcn_s_barrier();      \
                        __builtin_amdgcn_sched_barrier(0); } while (0)

// ---------------- prep: cast x -> bf16 AND transpose-cast W (one launch) ----------------
__global__ void mha_prep(const float* __restrict__ x, u16* __restrict__ xb,
                         const float* __restrict__ W0, const float* __restrict__ W1,
                         const float* __restrict__ W2, const float* __restrict__ W3,
                         u16* __restrict__ WtBase) {
    const int bid = blockIdx.x, tid = threadIdx.x;
    if (bid < 4096) {
        int i = (bid * 256 + tid) * 4;
        float4 v = *reinterpret_cast<const float4*>(x + i);
        ushort4 o;
        o.x = f2bf(v.x); o.y = f2bf(v.y); o.z = f2bf(v.z); o.w = f2bf(v.w);
        *reinterpret_cast<ushort4*>(xb + i) = o;
        return;
    }
    __shared__ float t[32][33];
    const int b2 = bid - 4096;
    const int mat = b2 >> 10, rem = b2 & 1023;
    const int cx = rem & 31, cy = rem >> 5;
    const float* W = (mat == 0) ? W0 : (mat == 1) ? W1 : (mat == 2) ? W2 : W3;
    u16* Wt = WtBase + (size_t)mat * DM * DM;
    const int c0 = cx * 32, r0 = cy * 32;
    const int tx = tid & 31, ty = tid >> 5;
#pragma unroll
    for (int i = ty; i < 32; i += 8)
        t[i][tx] = W[(size_t)(r0 + i) * DM + c0 + tx];
    __syncthreads();
#pragma unroll
    for (int i = ty; i < 32; i += 8)
        Wt[(size_t)(c0 + i) * DM + r0 + tx] = f2bf(t[tx][i]);
}

// ---------------- QKV GEMM v2 (r19): 128x192 tiles, 512 balanced blocks ----------------
__global__ __launch_bounds__(256, 2) void mha_gemm_qkv(const u16* __restrict__ xb, const u16* __restrict__ Wt,
                                                       const float* __restrict__ bq, const float* __restrict__ bk,
                                                       const float* __restrict__ bv, u16* __restrict__ qkv) {
    __shared__ __align__(16) char smem[81920];   // A[2][128][64] @0, B[2][192][64] @32768

    const int bid = blockIdx.x;
    const int bx = bid & 31, by = bid >> 5;      // 32 x 16
    const int m0 = bx * 128, n0g = by * 192;     // n0g in fused 0..3071

    const int tid = threadIdx.x;
    const int wave = tid >> 6, lane = tid & 63;
    const int lr = lane & 15, kg = lane >> 4;
    const int wr = wave >> 1, wc = wave & 1;     // wave owns 64x96

    auto STAGE = [&](int buf, int kt) {
#pragma unroll
        for (int i = 0; i < 4; ++i) {            // A: 16KB
            const int o = tid * 16 + i * 4096;
            const int r = o >> 7, slot = (o >> 4) & 7;
            gload_lds16(smem + buf * 16384 + o,
                        xb + (size_t)(m0 + r) * DM + kt * 64 + ((slot ^ (r & 7)) << 3));
        }
#pragma unroll
        for (int i = 0; i < 6; ++i) {            // B: 24KB (Wt rows n0g..n0g+191, fused)
            const int o = tid * 16 + i * 4096;
            const int r = o >> 7, slot = (o >> 4) & 7;
            gload_lds16(smem + 32768 + buf * 24576 + o,
                        Wt + (size_t)(n0g + r) * DM + kt * 64 + ((slot ^ (r & 7)) << 3));
        }
    };

    f32x4 acc[4][6] = {};
    STAGE(0, 0);
    for (int t = 0; t < 16; ++t) {
        if (t + 1 < 16) {
            STAGE((t + 1) & 1, t + 1);
            asm volatile("s_waitcnt vmcnt(10)" ::: "memory");
        } else {
            asm volatile("s_waitcnt vmcnt(0)" ::: "memory");
        }
        FENCE_BAR;
        const char* Ab = smem + (t & 1) * 16384;
        const char* Bb = smem + 32768 + (t & 1) * 24576;
#pragma unroll
        for (int ks = 0; ks < 2; ++ks) {
            s16x8 a[4], b[6];
#pragma unroll
            for (int m = 0; m < 4; ++m)
                a[m] = *reinterpret_cast<const s16x8*>(Ab + swz(wr * 64 + m * 16 + lr, ks * 64 + kg * 16));
#pragma unroll
            for (int n = 0; n < 6; ++n)
                b[n] = *reinterpret_cast<const s16x8*>(Bb + swz(wc * 96 + n * 16 + lr, ks * 64 + kg * 16));
#pragma unroll
            for (int m = 0; m < 4; ++m)
#pragma unroll
                for (int n = 0; n < 6; ++n)
                    acc[m][n] = __builtin_amdgcn_mfma_f32_16x16x32_bf16(a[m], b[n], acc[m][n], 0, 0, 0);
        }
        FENCE_BAR;
    }

    // direct-scatter epilogue; z resolved per 16-lane run (runs never cross 1024)
#pragma unroll
    for (int m = 0; m < 4; ++m)
#pragma unroll
        for (int n = 0; n < 6; ++n) {
            const int colg = n0g + wc * 96 + n * 16 + lr;    // 0..3071
            const int z = colg >> 10, coll = colg & 1023;
            const int h = coll >> 6, d = coll & 63;
            const float bv2 = ((z == 0) ? bq : (z == 1) ? bk : bv)[coll];
            const float scale = (z == 0) ? 0.125f * 1.44269504088896f : 1.0f;
            u16* Cout = qkv + (size_t)z * MM * DM;
#pragma unroll
            for (int j = 0; j < 4; ++j) {
                const int row = m0 + wr * 64 + m * 16 + kg * 4 + j;
                const int bb = row >> 11, s = row & (SS - 1);
                const float v = (acc[m][n][j] + bv2) * scale;
                if (z == 0) {
                    Cout[(((size_t)(bb * NH + h) * SS + s) * DK) + d] = f2bf(v);
                } else {
                    const int kt = s >> 6, r = s & 63;
                    const size_t tb = ((size_t)(bb * NH + h) * 32 + kt) * 4096;
                    const int bo = (z == 1) ? swz(r, d * 2)
                                            : swz(d, (r >> 1) * 4 + (r & 1) * 2);
                    Cout[tb + (bo >> 1)] = f2bf(v);
                }
            }
        }
}

// ---------------- gemm_out v2: 128x64 tiles, 512 blocks (2/CU), counted-vmcnt dbuf ----------------
// r19 analysis: old gemm_out = 256 blocks = 1 block/CU = 1 wave/SIMD (zero
// latency hiding, ~19us for 8.6GF). 128x64: grid 32x16=512 = 2/CU; LDS 48KB
// (A 2x16KB + B 2x8KB); vmcnt(6) gate; qkv-v2 STAGE pattern (pre-swizzled
// source + swz reads, conflict-free). B (Wo^T, 2MB) is L2-resident so the 2x
// A-re-read is free at 16% HBM.
__global__ __launch_bounds__(256, 2) void mha_gemm_out(const u16* __restrict__ AO, const u16* __restrict__ WoT,
                                                       const float* __restrict__ bo, float* __restrict__ out) {
    __shared__ __align__(16) char smem[49152];   // A[2][128][64] @0, B[2][64][64] @32768

    const int bid = blockIdx.x;
    const int bx = bid & 31, by = bid >> 5;      // 32 x 16
    const int m0 = bx * 128, n0 = by * 64;

    const int tid = threadIdx.x;
    const int wave = tid >> 6, lane = tid & 63;
    const int lr = lane & 15, kg = lane >> 4;
    const int wr = wave >> 1, wc = wave & 1;     // wave owns 64x32

    auto STAGE = [&](int buf, int kt) {
#pragma unroll
        for (int i = 0; i < 4; ++i) {            // A: 16KB
            const int o = tid * 16 + i * 4096;
            const int r = o >> 7, slot = (o >> 4) & 7;
            gload_lds16(smem + buf * 16384 + o,
                        AO + (size_t)(m0 + r) * DM + kt * 64 + ((slot ^ (r & 7)) << 3));
        }
#pragma unroll
        for (int i = 0; i < 2; ++i) {            // B: 8KB
            const int o = tid * 16 + i * 4096;
            const int r = o >> 7, slot = (o >> 4) & 7;
            gload_lds16(smem + 32768 + buf * 8192 + o,
                        WoT + (size_t)(n0 + r) * DM + kt * 64 + ((slot ^ (r & 7)) << 3));
        }
    };

    f32x4 acc[4][2] = {};
    STAGE(0, 0);
    for (int t = 0; t < 16; ++t) {
        if (t + 1 < 16) {
            STAGE((t + 1) & 1, t + 1);
            asm volatile("s_waitcnt vmcnt(6)" ::: "memory");
        } else {
            asm volatile("s_waitcnt vmcnt(0)" ::: "memory");
        }
        FENCE_BAR;
        const char* Ab = smem + (t & 1) * 16384;
        const char* Bb = smem + 32768 + (t & 1) * 8192;
#pragma unroll
        for (int ks = 0; ks < 2; ++ks) {
            s16x8 a[4], b[2];
#pragma unroll
            for (int m = 0; m < 4; ++m)
                a[m] = *reinterpret_cast<const s16x8*>(Ab + swz(wr * 64 + m * 16 + lr, ks * 64 + kg * 16));
#pragma unroll
            for (int n = 0; n < 2; ++n)
                b[n] = *reinterpret_cast<const s16x8*>(Bb + swz(wc * 32 + n * 16 + lr, ks * 64 + kg * 16));
#pragma unroll
            for (int m = 0; m < 4; ++m)
#pragma unroll
                for (int n = 0; n < 2; ++n)
                    acc[m][n] = __builtin_amdgcn_mfma_f32_16x16x32_bf16(a[m], b[n], acc[m][n], 0, 0, 0);
        }
        FENCE_BAR;
    }

#pragma unroll
    for (int m = 0; m < 4; ++m)
#pragma unroll
        for (int n = 0; n < 2; ++n) {
            const int col = n0 + wc * 32 + n * 16 + lr;
            const float bv = bo[col];
#pragma unroll
            for (int j = 0; j < 4; ++j) {
                const int row = m0 + wr * 64 + m * 16 + kg * 4 + j;
                out[(size_t)row * DM + col] = acc[m][n][j] + bv;
            }
        }
}

// ---------------- flash attention v11 (r18): QBLK=128, 8 waves ----------------
__device__ const unsigned char JQT[24] = {
    7,15,15, 14,14, 6,13,13, 12,12, 5,11,11, 10,10, 4,9,9, 8,8, 3,2,1,0};
__device__ const unsigned char JKS[24] = {
    0,0,16, 0,15, 0,0,14, 0,13, 0,0,12, 0,11, 0,0,10, 0,9, 0,0,0,0};
__device__ const unsigned char JKL[24] = {
    16,16,16, 15,15, 14,14,14, 13,13, 12,12,12, 11,11, 10,10,10, 9,9, 8,6,4,2};
__device__ const unsigned char JSL[24] = {
    255,14,15, 12,13, 255,10,11, 8,9, 255,6,7, 4,5, 255,2,3, 0,1, 255,255,255,255};

__global__ __launch_bounds__(512, 4) void mha_attn(const u16* __restrict__ Qb, const u16* __restrict__ Kswz,
                                                   const u16* __restrict__ Vtswz, u16* __restrict__ AO,
                                                   u16* __restrict__ Opart, float* __restrict__ lpart) {
    __shared__ __align__(16) char lds[49152];

    const int bid = blockIdx.x;
    const int bh  = bid & 31;
    const int job = bid >> 5;
    const int qt   = JQT[job];
    const int kst  = JKS[job];
    const int klen = JKL[job];
    const int slot = JSL[job];
    const int qb = qt * 128;

    const int tid = threadIdx.x, w = tid >> 6, lane = tid & 63;
    const int lr = lane & 15, kg = lane >> 4;

    const u16* Qh = Qb + (size_t)bh * SS * DK;
    const char* Ktiles = (const char*)(Kswz  + (size_t)bh * 32 * 4096);
    const char* Vtiles = (const char*)(Vtswz + (size_t)bh * 32 * 4096);
    const int bb = bh >> 4, hh = bh & (NH - 1);
    char* psb = lds + 32768 + w * 2048;
    const int o = tid * 16;

    const int qrow = qb + w * 16 + lr;
    const s16x8 qf0 = *reinterpret_cast<const s16x8*>(Qh + (size_t)qrow * DK + kg * 8);
    const s16x8 qf1 = *reinterpret_cast<const s16x8*>(Qh + (size_t)qrow * DK + 32 + kg * 8);
    f32x4 accO[4] = {};
    float lp = 0.f;

    const int kend = kst + klen;
    gload_lds16(lds + o,         Ktiles + kst * 8192 + o);
    gload_lds16(lds + 16384 + o, Vtiles + kst * 8192 + o);

    for (int t = kst; t < kend; ++t) {
        const int buf = (t - kst) & 1;
        asm volatile("s_waitcnt vmcnt(0)" ::: "memory");
        __syncthreads();
        if (t + 1 < kend) {
            gload_lds16(lds + (buf ^ 1) * 8192 + o,         Ktiles + (t + 1) * 8192 + o);
            gload_lds16(lds + 16384 + (buf ^ 1) * 8192 + o, Vtiles + (t + 1) * 8192 + o);
        }
        const char* ksb = lds + buf * 8192;
        const char* vtb = lds + 16384 + buf * 8192;
        const int kb = t * 64;

        f32x4 sc[4];
#pragma unroll
        for (int f = 0; f < 4; ++f) {
            s16x8 kf0 = *reinterpret_cast<const s16x8*>(ksb + swz(f * 16 + lr, kg * 16));
            s16x8 kf1 = *reinterpret_cast<const s16x8*>(ksb + swz(f * 16 + lr, 64 + kg * 16));
            f32x4 s = {};
            s = __builtin_amdgcn_mfma_f32_16x16x32_bf16(kf0, qf0, s, 0, 0, 0);
            s = __builtin_amdgcn_mfma_f32_16x16x32_bf16(kf1, qf1, s, 0, 0, 0);
            sc[f] = s;
        }
#pragma unroll
        for (int f = 0; f < 4; ++f)
#pragma unroll
            for (int j = 0; j < 4; ++j)
                sc[f][j] = __builtin_amdgcn_exp2f(sc[f][j]);
        if (kb + 63 > qb + w * 16) {
            const int qg = qb + w * 16 + lr;
#pragma unroll
            for (int f = 0; f < 4; ++f) {
                const int kc = kb + f * 16 + kg * 4;
#pragma unroll
                for (int j = 0; j < 4; ++j)
                    if (kc + j > qg) sc[f][j] = 0.f;
            }
        }
        float fs0 = 0.f, fs1 = 0.f;
#pragma unroll
        for (int f = 0; f < 4; ++f) {
            u32x2 pp;
            pp[0] = cvtpk(sc[f][0], sc[f][1]);
            pp[1] = cvtpk(sc[f][2], sc[f][3]);
            *reinterpret_cast<u32x2*>(psb + swz(lr, f * 32 + kg * 8)) = pp;
            const float s01 = sc[f][0] + sc[f][1], s23 = sc[f][2] + sc[f][3];
            if (f & 1) fs1 += s01 + s23; else fs0 += s01 + s23;
        }
        lp += fs0 + fs1;

        const s16x8 pf0 = *reinterpret_cast<const s16x8*>(psb + swz(lr, kg * 16));
        const s16x8 pf1 = *reinterpret_cast<const s16x8*>(psb + swz(lr, 64 + kg * 16));
#pragma unroll
        for (int db = 0; db < 4; ++db) {
            s16x8 vf0 = *reinterpret_cast<const s16x8*>(vtb + swz(db * 16 + lr, kg * 16));
            s16x8 vf1 = *reinterpret_cast<const s16x8*>(vtb + swz(db * 16 + lr, 64 + kg * 16));
            accO[db] = __builtin_amdgcn_mfma_f32_16x16x32_bf16(pf0, vf0, accO[db], 0, 0, 0);
            accO[db] = __builtin_amdgcn_mfma_f32_16x16x32_bf16(pf1, vf1, accO[db], 0, 0, 0);
        }
    }

    lp += __shfl_xor(lp, 16, 64);
    lp += __shfl_xor(lp, 32, 64);

    if (slot == 255) {
        float inv[4];
#pragma unroll
        for (int j = 0; j < 4; ++j)
            inv[j] = 1.0f / __shfl(lp, kg * 4 + j, 64);
#pragma unroll
        for (int db = 0; db < 4; ++db) {
            const int d = db * 16 + lr;
#pragma unroll
            for (int j = 0; j < 4; ++j) {
                const int s = qb + w * 16 + kg * 4 + j;
                AO[((size_t)(bb * SS + s)) * DM + hh * DK + d] = f2bf(accO[db][j] * inv[j]);
            }
        }
    } else {
        const int idx = bh * 16 + slot;
        u16* Od = Opart + (size_t)idx * 8192;
#pragma unroll
        for (int db = 0; db < 4; ++db) {
            const int d = db * 16 + lr;
#pragma unroll
            for (int j = 0; j < 4; ++j)
                Od[(w * 16 + kg * 4 + j) * 64 + d] = f2bf(accO[db][j]);
        }
        if (lane < 16)
            lpart[idx * 128 + w * 16 + lane] = lp;
    }
}

// combine partials for split q-tiles (qt 8..15): AO = (O0+O1)/(l0+l1)
__global__ __launch_bounds__(256) void mha_combine(const u16* __restrict__ Opart,
                                                   const float* __restrict__ lpart,
                                                   u16* __restrict__ AO) {
    const int blk = blockIdx.x;          // 0..255
    const int bh = blk & 31, q = blk >> 5;
    const int qt = 8 + q;
    const int t = threadIdx.x;
    const int row = t >> 1, c0 = (t & 1) * 32;
    const int idx0 = bh * 16 + q * 2;
    const u16* O0 = Opart + (size_t)idx0 * 8192 + row * 64 + c0;
    const u16* O1 = O0 + 8192;
    const float l = lpart[idx0 * 128 + row] + lpart[(idx0 + 1) * 128 + row];
    const float inv = 1.0f / l;
    const int bb = bh >> 4, hh = bh & (NH - 1);
    const int s = qt * 128 + row;
    u16* dst = AO + ((size_t)(bb * SS + s)) * DM + hh * DK + c0;
#pragma unroll
    for (int h = 0; h < 4; ++h) {
        s16x8 a = *reinterpret_cast<const s16x8*>(O0 + h * 8);
        s16x8 b = *reinterpret_cast<const s16x8*>(O1 + h * 8);
        u16* ap = (u16*)&a; u16* bp = (u16*)&b;
        u16 ov[8];
#pragma unroll
        for (int i = 0; i < 8; ++i)
            ov[i] = f2bf((bf2f(ap[i]) + bf2f(bp[i])) * inv);
        *reinterpret_cast<ushort4*>(dst + h * 8) = *reinterpret_cast<ushort4*>(&ov[0]);
        *reinterpret_cast<ushort4*>(dst + h * 8 + 4) = *reinterpret_cast<ushort4*>(&ov[4]);
    }
}

extern "C" void kernel_launch(void* const* d_in, const int* in_sizes, int n_in,
                              void* d_out, int out_size, void* d_ws, size_t ws_size,
                              hipStream_t stream) {
    const float* x  = (const float*)d_in[0];
    const float* Wq = (const float*)d_in[2];
    const float* bq = (const float*)d_in[3];
    const float* Wk = (const float*)d_in[4];
    const float* bk = (const float*)d_in[5];
    const float* Wv = (const float*)d_in[6];
    const float* bv = (const float*)d_in[7];
    const float* Wo = (const float*)d_in[8];
    const float* bo = (const float*)d_in[9];
    float* out = (float*)d_out;

    char* ws = (char*)d_ws;
    u16* xb  = (u16*)(ws);                       // 8 MB (dead after gemm_qkv)
    u16* Wt  = (u16*)(ws + ((size_t)8  << 20));  // 8 MB: Wq^T|Wk^T|Wv^T|Wo^T
    u16* qkv = (u16*)(ws + ((size_t)16 << 20));  // 24 MB: Q | K-swz tiles | V^T-swz tiles
    u16* AO  = (u16*)(ws + ((size_t)40 << 20));  // 8 MB
    u16*   Opart = (u16*)(ws);                       // 8 MB over xb
    float* lpart = (float*)(ws + ((size_t)8 << 20)); // 256 KB over Wq^T

    mha_prep<<<dim3(8192), dim3(256), 0, stream>>>(x, xb, Wq, Wk, Wv, Wo, Wt);
    mha_gemm_qkv<<<dim3(512), dim3(256), 0, stream>>>(xb, Wt, bq, bk, bv, qkv);
    mha_attn<<<dim3(768), dim3(512), 0, stream>>>(qkv, qkv + (size_t)4194304, qkv + (size_t)8388608,
                                                  AO, Opart, lpart);
    mha_combine<<<dim3(256), dim3(256), 0, stream>>>(Opart, lpart, AO);
    mha_gemm_out<<<dim3(512), dim3(256), 0, stream>>>(AO, Wt + (size_t)3 * DM * DM, bo, out);
}

// Round 21
// 95.251 us; speedup vs baseline: 1.1466x; 1.0321x over previous
//
#include <hip/hip_runtime.h>
#include <hip/hip_bf16.h>
#include <cstdint>
#include <cmath>

#define DM 1024
#define NH 16
#define DK 64
#define NB 2
#define SS 2048
#define MM (NB*SS)   // 4096 rows

typedef unsigned short u16;
typedef uint32_t u32;
typedef __attribute__((ext_vector_type(4))) float f32x4;
typedef __attribute__((ext_vector_type(8))) short s16x8;
typedef __attribute__((ext_vector_type(2))) uint32_t u32x2;

__device__ __forceinline__ u16 f2bf(float f) {
    __hip_bfloat16 h = __float2bfloat16(f);
    return __builtin_bit_cast(u16, h);
}

__device__ __forceinline__ u32 cvtpk(float a, float b) {
    u32 r;
    asm("v_cvt_pk_bf16_f32 %0, %1, %2" : "=v"(r) : "v"(a), "v"(b));
    return r;
}

__device__ __forceinline__ void gload_lds16(void* lds, const void* g) {
    __builtin_amdgcn_global_load_lds(
        (const __attribute__((address_space(1))) uint32_t*)g,
        (__attribute__((address_space(3))) uint32_t*)lds, 16, 0, 0);
}

// XOR-swizzled byte offset within a [rows][128B] LDS tile: 16B slot ^= row&7.
__device__ __forceinline__ int swz(int row, int cb) {
    return row * 128 + ((((cb) >> 4) ^ (row & 7)) << 4) + ((cb) & 15);
}

#define FENCE_BAR  do { __builtin_amdgcn_sched_barrier(0); \
                        __builtin_amdgcn_s_barrier();      \
                        __builtin_amdgcn_sched_barrier(0); } while (0)

// ---------------- prep: cast x -> bf16 AND transpose-cast W (one launch) ----------------
__global__ void mha_prep(const float* __restrict__ x, u16* __restrict__ xb,
                         const float* __restrict__ W0, const float* __restrict__ W1,
                         const float* __restrict__ W2, const float* __restrict__ W3,
                         u16* __restrict__ WtBase) {
    const int bid = blockIdx.x, tid = threadIdx.x;
    if (bid < 4096) {
        int i = (bid * 256 + tid) * 4;
        float4 v = *reinterpret_cast<const float4*>(x + i);
        ushort4 o;
        o.x = f2bf(v.x); o.y = f2bf(v.y); o.z = f2bf(v.z); o.w = f2bf(v.w);
        *reinterpret_cast<ushort4*>(xb + i) = o;
        return;
    }
    __shared__ float t[32][33];
    const int b2 = bid - 4096;
    const int mat = b2 >> 10, rem = b2 & 1023;
    const int cx = rem & 31, cy = rem >> 5;
    const float* W = (mat == 0) ? W0 : (mat == 1) ? W1 : (mat == 2) ? W2 : W3;
    u16* Wt = WtBase + (size_t)mat * DM * DM;
    const int c0 = cx * 32, r0 = cy * 32;
    const int tx = tid & 31, ty = tid >> 5;
#pragma unroll
    for (int i = ty; i < 32; i += 8)
        t[i][tx] = W[(size_t)(r0 + i) * DM + c0 + tx];
    __syncthreads();
#pragma unroll
    for (int i = ty; i < 32; i += 8)
        Wt[(size_t)(c0 + i) * DM + r0 + tx] = f2bf(t[tx][i]);
}

// ---------------- QKV GEMM v2 (r19): 128x192 tiles, 512 balanced blocks ----------------
__global__ __launch_bounds__(256, 2) void mha_gemm_qkv(const u16* __restrict__ xb, const u16* __restrict__ Wt,
                                                       const float* __restrict__ bq, const float* __restrict__ bk,
                                                       const float* __restrict__ bv, u16* __restrict__ qkv) {
    __shared__ __align__(16) char smem[81920];   // A[2][128][64] @0, B[2][192][64] @32768

    const int bid = blockIdx.x;
    const int bx = bid & 31, by = bid >> 5;      // 32 x 16
    const int m0 = bx * 128, n0g = by * 192;     // n0g in fused 0..3071

    const int tid = threadIdx.x;
    const int wave = tid >> 6, lane = tid & 63;
    const int lr = lane & 15, kg = lane >> 4;
    const int wr = wave >> 1, wc = wave & 1;     // wave owns 64x96

    auto STAGE = [&](int buf, int kt) {
#pragma unroll
        for (int i = 0; i < 4; ++i) {            // A: 16KB
            const int o = tid * 16 + i * 4096;
            const int r = o >> 7, slot = (o >> 4) & 7;
            gload_lds16(smem + buf * 16384 + o,
                        xb + (size_t)(m0 + r) * DM + kt * 64 + ((slot ^ (r & 7)) << 3));
        }
#pragma unroll
        for (int i = 0; i < 6; ++i) {            // B: 24KB (Wt rows n0g..n0g+191, fused)
            const int o = tid * 16 + i * 4096;
            const int r = o >> 7, slot = (o >> 4) & 7;
            gload_lds16(smem + 32768 + buf * 24576 + o,
                        Wt + (size_t)(n0g + r) * DM + kt * 64 + ((slot ^ (r & 7)) << 3));
        }
    };

    f32x4 acc[4][6] = {};
    STAGE(0, 0);
    for (int t = 0; t < 16; ++t) {
        if (t + 1 < 16) {
            STAGE((t + 1) & 1, t + 1);
            asm volatile("s_waitcnt vmcnt(10)" ::: "memory");
        } else {
            asm volatile("s_waitcnt vmcnt(0)" ::: "memory");
        }
        FENCE_BAR;
        const char* Ab = smem + (t & 1) * 16384;
        const char* Bb = smem + 32768 + (t & 1) * 24576;
#pragma unroll
        for (int ks = 0; ks < 2; ++ks) {
            s16x8 a[4], b[6];
#pragma unroll
            for (int m = 0; m < 4; ++m)
                a[m] = *reinterpret_cast<const s16x8*>(Ab + swz(wr * 64 + m * 16 + lr, ks * 64 + kg * 16));
#pragma unroll
            for (int n = 0; n < 6; ++n)
                b[n] = *reinterpret_cast<const s16x8*>(Bb + swz(wc * 96 + n * 16 + lr, ks * 64 + kg * 16));
#pragma unroll
            for (int m = 0; m < 4; ++m)
#pragma unroll
                for (int n = 0; n < 6; ++n)
                    acc[m][n] = __builtin_amdgcn_mfma_f32_16x16x32_bf16(a[m], b[n], acc[m][n], 0, 0, 0);
        }
        FENCE_BAR;
    }

    // direct-scatter epilogue; z resolved per 16-lane run (runs never cross 1024)
#pragma unroll
    for (int m = 0; m < 4; ++m)
#pragma unroll
        for (int n = 0; n < 6; ++n) {
            const int colg = n0g + wc * 96 + n * 16 + lr;    // 0..3071
            const int z = colg >> 10, coll = colg & 1023;
            const int h = coll >> 6, d = coll & 63;
            const float bv2 = ((z == 0) ? bq : (z == 1) ? bk : bv)[coll];
            const float scale = (z == 0) ? 0.125f * 1.44269504088896f : 1.0f;
            u16* Cout = qkv + (size_t)z * MM * DM;
#pragma unroll
            for (int j = 0; j < 4; ++j) {
                const int row = m0 + wr * 64 + m * 16 + kg * 4 + j;
                const int bb = row >> 11, s = row & (SS - 1);
                const float v = (acc[m][n][j] + bv2) * scale;
                if (z == 0) {
                    Cout[(((size_t)(bb * NH + h) * SS + s) * DK) + d] = f2bf(v);
                } else {
                    const int kt = s >> 6, r = s & 63;
                    const size_t tb = ((size_t)(bb * NH + h) * 32 + kt) * 4096;
                    const int bo = (z == 1) ? swz(r, d * 2)
                                            : swz(d, (r >> 1) * 4 + (r & 1) * 2);
                    Cout[tb + (bo >> 1)] = f2bf(v);
                }
            }
        }
}

// ---------------- gemm_out v2 (r20): 128x64 tiles, 512 blocks, counted-vmcnt dbuf ----------------
__global__ __launch_bounds__(256, 2) void mha_gemm_out(const u16* __restrict__ AO, const u16* __restrict__ WoT,
                                                       const float* __restrict__ bo, float* __restrict__ out) {
    __shared__ __align__(16) char smem[49152];   // A[2][128][64] @0, B[2][64][64] @32768

    const int bid = blockIdx.x;
    const int bx = bid & 31, by = bid >> 5;      // 32 x 16
    const int m0 = bx * 128, n0 = by * 64;

    const int tid = threadIdx.x;
    const int wave = tid >> 6, lane = tid & 63;
    const int lr = lane & 15, kg = lane >> 4;
    const int wr = wave >> 1, wc = wave & 1;     // wave owns 64x32

    auto STAGE = [&](int buf, int kt) {
#pragma unroll
        for (int i = 0; i < 4; ++i) {            // A: 16KB
            const int o = tid * 16 + i * 4096;
            const int r = o >> 7, slot = (o >> 4) & 7;
            gload_lds16(smem + buf * 16384 + o,
                        AO + (size_t)(m0 + r) * DM + kt * 64 + ((slot ^ (r & 7)) << 3));
        }
#pragma unroll
        for (int i = 0; i < 2; ++i) {            // B: 8KB
            const int o = tid * 16 + i * 4096;
            const int r = o >> 7, slot = (o >> 4) & 7;
            gload_lds16(smem + 32768 + buf * 8192 + o,
                        WoT + (size_t)(n0 + r) * DM + kt * 64 + ((slot ^ (r & 7)) << 3));
        }
    };

    f32x4 acc[4][2] = {};
    STAGE(0, 0);
    for (int t = 0; t < 16; ++t) {
        if (t + 1 < 16) {
            STAGE((t + 1) & 1, t + 1);
            asm volatile("s_waitcnt vmcnt(6)" ::: "memory");
        } else {
            asm volatile("s_waitcnt vmcnt(0)" ::: "memory");
        }
        FENCE_BAR;
        const char* Ab = smem + (t & 1) * 16384;
        const char* Bb = smem + 32768 + (t & 1) * 8192;
#pragma unroll
        for (int ks = 0; ks < 2; ++ks) {
            s16x8 a[4], b[2];
#pragma unroll
            for (int m = 0; m < 4; ++m)
                a[m] = *reinterpret_cast<const s16x8*>(Ab + swz(wr * 64 + m * 16 + lr, ks * 64 + kg * 16));
#pragma unroll
            for (int n = 0; n < 2; ++n)
                b[n] = *reinterpret_cast<const s16x8*>(Bb + swz(wc * 32 + n * 16 + lr, ks * 64 + kg * 16));
#pragma unroll
            for (int m = 0; m < 4; ++m)
#pragma unroll
                for (int n = 0; n < 2; ++n)
                    acc[m][n] = __builtin_amdgcn_mfma_f32_16x16x32_bf16(a[m], b[n], acc[m][n], 0, 0, 0);
        }
        FENCE_BAR;
    }

#pragma unroll
    for (int m = 0; m < 4; ++m)
#pragma unroll
        for (int n = 0; n < 2; ++n) {
            const int col = n0 + wc * 32 + n * 16 + lr;
            const float bv = bo[col];
#pragma unroll
            for (int j = 0; j < 4; ++j) {
                const int row = m0 + wr * 64 + m * 16 + kg * 4 + j;
                out[(size_t)row * DM + col] = acc[m][n][j] + bv;
            }
        }
}

// ---------------- flash attention v12: non-split, complementary co-CU pairing ----------------
// 512 blocks (16 qt x 32 bh) of 512 thr = EXACTLY 2 blocks/CU, whole grid
// co-resident (no backfill needed). Blocks bid and bid+256 share a CU under
// round-robin; PERM[j] + PERM[j+8] = 15 makes every co-CU pair run exactly
// (2qt1+2)+(2qt2+2) = 34 k-iters. Removes the combine kernel, its launch gap,
// and ~8MB of partial traffic. bh = bid&31 keeps head->XCD pinning (256%8=0).
__device__ const unsigned char PERM[16] = {15,14,13,12,11,10,9,8, 0,1,2,3,4,5,6,7};

__global__ __launch_bounds__(512, 4) void mha_attn(const u16* __restrict__ Qb, const u16* __restrict__ Kswz,
                                                   const u16* __restrict__ Vtswz, u16* __restrict__ AO) {
    // LDS: K dbuf 2x8KB @0 | V^T dbuf 2x8KB @16384 | Ps[8 waves][2KB] @32768
    __shared__ __align__(16) char lds[49152];

    const int bid = blockIdx.x;
    const int bh  = bid & 31;
    const int qt  = PERM[bid >> 5];
    const int qb  = qt * 128;
    const int nkt = 2 * qt + 2;

    const int tid = threadIdx.x, w = tid >> 6, lane = tid & 63;
    const int lr = lane & 15, kg = lane >> 4;

    const u16* Qh = Qb + (size_t)bh * SS * DK;
    const char* Ktiles = (const char*)(Kswz  + (size_t)bh * 32 * 4096);
    const char* Vtiles = (const char*)(Vtswz + (size_t)bh * 32 * 4096);
    const int bb = bh >> 4, hh = bh & (NH - 1);
    char* psb = lds + 32768 + w * 2048;
    const int o = tid * 16;

    const int qrow = qb + w * 16 + lr;
    const s16x8 qf0 = *reinterpret_cast<const s16x8*>(Qh + (size_t)qrow * DK + kg * 8);
    const s16x8 qf1 = *reinterpret_cast<const s16x8*>(Qh + (size_t)qrow * DK + 32 + kg * 8);
    f32x4 accO[4] = {};
    float lp = 0.f;

    gload_lds16(lds + o,         Ktiles + o);
    gload_lds16(lds + 16384 + o, Vtiles + o);

    for (int t = 0; t < nkt; ++t) {
        const int buf = t & 1;
        asm volatile("s_waitcnt vmcnt(0)" ::: "memory");
        __syncthreads();
        if (t + 1 < nkt) {
            gload_lds16(lds + (buf ^ 1) * 8192 + o,         Ktiles + (t + 1) * 8192 + o);
            gload_lds16(lds + 16384 + (buf ^ 1) * 8192 + o, Vtiles + (t + 1) * 8192 + o);
        }
        const char* ksb = lds + buf * 8192;
        const char* vtb = lds + 16384 + buf * 8192;
        const int kb = t * 64;

        // swapped QK^T: lane holds P[q=lr][k=f*16+kg*4+j]
        f32x4 sc[4];
#pragma unroll
        for (int f = 0; f < 4; ++f) {
            s16x8 kf0 = *reinterpret_cast<const s16x8*>(ksb + swz(f * 16 + lr, kg * 16));
            s16x8 kf1 = *reinterpret_cast<const s16x8*>(ksb + swz(f * 16 + lr, 64 + kg * 16));
            f32x4 s = {};
            s = __builtin_amdgcn_mfma_f32_16x16x32_bf16(kf0, qf0, s, 0, 0, 0);
            s = __builtin_amdgcn_mfma_f32_16x16x32_bf16(kf1, qf1, s, 0, 0, 0);
            sc[f] = s;
        }
#pragma unroll
        for (int f = 0; f < 4; ++f)
#pragma unroll
            for (int j = 0; j < 4; ++j)
                sc[f][j] = __builtin_amdgcn_exp2f(sc[f][j]);
        if (kb + 63 > qb + w * 16) {      // wave-uniform causal-frontier check
            const int qg = qb + w * 16 + lr;
#pragma unroll
            for (int f = 0; f < 4; ++f) {
                const int kc = kb + f * 16 + kg * 4;
#pragma unroll
                for (int j = 0; j < 4; ++j)
                    if (kc + j > qg) sc[f][j] = 0.f;
            }
        }
        float fs0 = 0.f, fs1 = 0.f;
#pragma unroll
        for (int f = 0; f < 4; ++f) {
            u32x2 pp;
            pp[0] = cvtpk(sc[f][0], sc[f][1]);
            pp[1] = cvtpk(sc[f][2], sc[f][3]);
            *reinterpret_cast<u32x2*>(psb + swz(lr, f * 32 + kg * 8)) = pp;
            const float s01 = sc[f][0] + sc[f][1], s23 = sc[f][2] + sc[f][3];
            if (f & 1) fs1 += s01 + s23; else fs0 += s01 + s23;
        }
        lp += fs0 + fs1;

        const s16x8 pf0 = *reinterpret_cast<const s16x8*>(psb + swz(lr, kg * 16));
        const s16x8 pf1 = *reinterpret_cast<const s16x8*>(psb + swz(lr, 64 + kg * 16));
#pragma unroll
        for (int db = 0; db < 4; ++db) {
            s16x8 vf0 = *reinterpret_cast<const s16x8*>(vtb + swz(db * 16 + lr, kg * 16));
            s16x8 vf1 = *reinterpret_cast<const s16x8*>(vtb + swz(db * 16 + lr, 64 + kg * 16));
            accO[db] = __builtin_amdgcn_mfma_f32_16x16x32_bf16(pf0, vf0, accO[db], 0, 0, 0);
            accO[db] = __builtin_amdgcn_mfma_f32_16x16x32_bf16(pf1, vf1, accO[db], 0, 0, 0);
        }
    }

    // complete row sums over the 4 kg-lanes holding row q=lr
    lp += __shfl_xor(lp, 16, 64);
    lp += __shfl_xor(lp, 32, 64);

    float inv[4];
#pragma unroll
    for (int j = 0; j < 4; ++j)
        inv[j] = 1.0f / __shfl(lp, kg * 4 + j, 64);
#pragma unroll
    for (int db = 0; db < 4; ++db) {
        const int d = db * 16 + lr;
#pragma unroll
        for (int j = 0; j < 4; ++j) {
            const int s = qb + w * 16 + kg * 4 + j;
            AO[((size_t)(bb * SS + s)) * DM + hh * DK + d] = f2bf(accO[db][j] * inv[j]);
        }
    }
}

extern "C" void kernel_launch(void* const* d_in, const int* in_sizes, int n_in,
                              void* d_out, int out_size, void* d_ws, size_t ws_size,
                              hipStream_t stream) {
    const float* x  = (const float*)d_in[0];
    const float* Wq = (const float*)d_in[2];
    const float* bq = (const float*)d_in[3];
    const float* Wk = (const float*)d_in[4];
    const float* bk = (const float*)d_in[5];
    const float* Wv = (const float*)d_in[6];
    const float* bv = (const float*)d_in[7];
    const float* Wo = (const float*)d_in[8];
    const float* bo = (const float*)d_in[9];
    float* out = (float*)d_out;

    char* ws = (char*)d_ws;
    u16* xb  = (u16*)(ws);                       // 8 MB (dead after gemm_qkv)
    u16* Wt  = (u16*)(ws + ((size_t)8  << 20));  // 8 MB: Wq^T|Wk^T|Wv^T|Wo^T
    u16* qkv = (u16*)(ws + ((size_t)16 << 20));  // 24 MB: Q | K-swz tiles | V^T-swz tiles
    u16* AO  = (u16*)(ws + ((size_t)40 << 20));  // 8 MB

    mha_prep<<<dim3(8192), dim3(256), 0, stream>>>(x, xb, Wq, Wk, Wv, Wo, Wt);
    mha_gemm_qkv<<<dim3(512), dim3(256), 0, stream>>>(xb, Wt, bq, bk, bv, qkv);
    mha_attn<<<dim3(512), dim3(512), 0, stream>>>(qkv, qkv + (size_t)4194304, qkv + (size_t)8388608, AO);
    mha_gemm_out<<<dim3(512), dim3(256), 0, stream>>>(AO, Wt + (size_t)3 * DM * DM, bo, out);
}